// Round 15
// baseline (177.267 us; speedup 1.0000x reference)
//
#include <hip/hip_runtime.h>
#include <hip/hip_bf16.h>

typedef unsigned short u16;
typedef __attribute__((ext_vector_type(8))) short short8;
typedef __attribute__((ext_vector_type(4))) float f32x4;

#define BATCH_ 32

static __device__ __forceinline__ float b2f(u16 u) {
  union { unsigned int i; float f; } v; v.i = ((unsigned int)u) << 16; return v.f;
}
static __device__ __forceinline__ u16 f2b(float x) {
  unsigned int i = __float_as_uint(x);
  unsigned int r = (i + 0x7fffu + ((i >> 16) & 1u)) >> 16;
  return (u16)r;
}

#define GCAST(p) ((const __attribute__((address_space(1))) void*)(p))
#define LCAST(p) ((__attribute__((address_space(3))) void*)(p))

// ---- dual-source f32 -> bf16 (n1, n2 % 4 == 0); one launch for two arrays
__global__ __launch_bounds__(256) void cvt_bf16_dual(
    const float* __restrict__ s1, u16* __restrict__ d1, int n1,
    const float* __restrict__ s2, u16* __restrict__ d2, int n2) {
  int i = (blockIdx.x * 256 + threadIdx.x) * 4;
  const float* s; u16* d; int idx;
  if (i < n1) { s = s1; d = d1; idx = i; }
  else { idx = i - n1; if (idx >= n2) return; s = s2; d = d2; }
  float4 v = *(const float4*)(s + idx);
  ushort4 o;
  o.x = f2b(v.x); o.y = f2b(v.y); o.z = f2b(v.z); o.w = f2b(v.w);
  *(ushort4*)(d + idx) = o;
}

// ---- fused transpose+scale: scaled[b][k][o] = other[o][k] * fix[b][o]
__global__ __launch_bounds__(256) void transpose_scale(
    const float* __restrict__ other, const float* __restrict__ fix,
    u16* __restrict__ scaled) {
  __shared__ float tile[32][33];   // [o_local][k_local]
  __shared__ float fixs[32][33];   // [b][o_local]
  int k0 = blockIdx.x * 32, o0 = blockIdx.y * 32;
  int tx = threadIdx.x & 31, ty = threadIdx.x >> 5;   // ty 0..7
  #pragma unroll
  for (int i = 0; i < 32; i += 8)
    tile[ty + i][tx] = other[(long long)(o0 + ty + i) * 512 + k0 + tx];
  #pragma unroll
  for (int i = 0; i < 32; i += 8)
    fixs[ty + i][tx] = fix[(long long)(ty + i) * 2048 + o0 + tx];
  __syncthreads();
  int kk = threadIdx.x >> 4;          // 0..15
  int oo = (threadIdx.x & 15) * 2;    // 0,2,..30
  #pragma unroll 4
  for (int b = 0; b < 32; ++b) {
    #pragma unroll
    for (int p = 0; p < 2; ++p) {
      int k = kk + p * 16;
      ushort2 w;
      w.x = f2b(tile[oo][k] * fixs[b][oo]);
      w.y = f2b(tile[oo + 1][k] * fixs[b][oo + 1]);
      *(ushort2*)(scaled + ((long long)(b * 512 + k0 + k) * 2048 + o0 + oo)) = w;
    }
  }
}

// ---- masked row softmax on bf16 S
__global__ __launch_bounds__(256) void softmax_mask(const u16* __restrict__ S,
                                                    const int* __restrict__ mask,
                                                    u16* __restrict__ P, int N) {
  const float scale = 0.044194173824159216f; // 1/sqrt(512)
  int row = blockIdx.x;
  int t = threadIdx.x;
  long long base = (long long)row * N;
  float vals[8]; int msk[8];
  float mx = -3.0e38f;
  #pragma unroll
  for (int i = 0; i < 8; ++i) {
    int c = t + i * 256;
    float s = b2f(S[base + c]) * scale;
    int m = mask[base + c];
    vals[i] = s; msk[i] = m;
    if (!m) mx = fmaxf(mx, s);
  }
  #pragma unroll
  for (int off = 32; off; off >>= 1) mx = fmaxf(mx, __shfl_xor(mx, off));
  __shared__ float sred[4];
  if ((t & 63) == 0) sred[t >> 6] = mx;
  __syncthreads();
  mx = fmaxf(fmaxf(sred[0], sred[1]), fmaxf(sred[2], sred[3]));
  __syncthreads();
  float e[8]; float sum = 0.f;
  #pragma unroll
  for (int i = 0; i < 8; ++i) {
    e[i] = msk[i] ? 0.f : __expf(vals[i] - mx);
    sum += e[i];
  }
  #pragma unroll
  for (int off = 32; off; off >>= 1) sum += __shfl_xor(sum, off);
  if ((t & 63) == 0) sred[t >> 6] = sum;
  __syncthreads();
  sum = sred[0] + sred[1] + sred[2] + sred[3];
  float inv = (sum > 0.f) ? (1.f / sum) : 0.f;
  #pragma unroll
  for (int i = 0; i < 8; ++i) {
    int c = t + i * 256;
    P[base + c] = f2b(e[i] * inv);
  }
}

// ========== r2-proven 128x128 / BK=32 GEMM (small GEMMs: Q|K proj, S) ======
#define GBM 128
#define GBN 128
#define GBK 32

template<int EPI>
__global__ __launch_bounds__(256) void gemm_lds(
    const u16* __restrict__ A, const u16* __restrict__ Bt,
    const float* __restrict__ bias,
    const u16* __restrict__ Bt2, const float* __restrict__ bias2,
    float* __restrict__ outF, u16* __restrict__ outB,
    int M, int N, int K) {
  __shared__ u16 sA[GBM * GBK];
  __shared__ u16 sB[GBN * GBK];
  int m0 = blockIdx.y * GBM, n0 = blockIdx.x * GBN;
  if (EPI == 0) {
    if (2 * blockIdx.y >= gridDim.y) { Bt = Bt2; bias = bias2; }
  }
  int t = threadIdx.x;
  int wid = t >> 6, lane = t & 63;
  int wm = (wid >> 1) * 64, wn = (wid & 1) * 64;
  int lr = lane & 15, lq = lane >> 4;
  int srow = lane >> 2, schunk = (lane & 3) * 8;

  f32x4 acc[4][4];
  #pragma unroll
  for (int i = 0; i < 4; ++i)
    #pragma unroll
    for (int j = 0; j < 4; ++j)
      acc[i][j] = (f32x4){0.f, 0.f, 0.f, 0.f};

  const u16* gA = A + (long long)(m0 + wid * 32 + srow) * K + schunk;
  const u16* gB = Bt + (long long)(n0 + wid * 32 + srow) * K + schunk;
  u16* lA = &sA[(wid * 32) * GBK];
  u16* lB = &sB[(wid * 32) * GBK];
  const long long rowskip = (long long)16 * K;

  for (int k0 = 0; k0 < K; k0 += GBK) {
    __builtin_amdgcn_global_load_lds(GCAST(gA + k0),           LCAST(lA),            16, 0, 0);
    __builtin_amdgcn_global_load_lds(GCAST(gA + k0 + rowskip), LCAST(lA + 16 * GBK), 16, 0, 0);
    __builtin_amdgcn_global_load_lds(GCAST(gB + k0),           LCAST(lB),            16, 0, 0);
    __builtin_amdgcn_global_load_lds(GCAST(gB + k0 + rowskip), LCAST(lB + 16 * GBK), 16, 0, 0);
    __syncthreads();
    short8 af[4], bf[4];
    #pragma unroll
    for (int i = 0; i < 4; ++i)
      af[i] = *(const short8*)&sA[(wm + i * 16 + lr) * GBK + lq * 8];
    #pragma unroll
    for (int j = 0; j < 4; ++j)
      bf[j] = *(const short8*)&sB[(wn + j * 16 + lr) * GBK + lq * 8];
    #pragma unroll
    for (int i = 0; i < 4; ++i)
      #pragma unroll
      for (int j = 0; j < 4; ++j)
        acc[i][j] = __builtin_amdgcn_mfma_f32_16x16x32_bf16(af[i], bf[j], acc[i][j], 0, 0, 0);
    __syncthreads();
  }

  #pragma unroll
  for (int i = 0; i < 4; ++i) {
    #pragma unroll
    for (int j = 0; j < 4; ++j) {
      int col = n0 + wn + j * 16 + lr;
      #pragma unroll
      for (int r = 0; r < 4; ++r) {
        int row = m0 + wm + i * 16 + lq * 4 + r;
        float v = acc[i][j][r];
        if (EPI == 0) {
          outB[(long long)row * N + col] = f2b(v + bias[col]);
        } else if (EPI == 1) {
          outF[(long long)row * N + col] = v;
        } else {
          outB[(long long)row * N + col] = f2b(v);
        }
      }
    }
  }
}

// ========== 8-phase sliding-window GEMM: 256x256, BK=64, dbuf-per-K-tile ===
// C[m][n] = sum_k A[m][k]*Bt[n][k]; epilogue scatter n -> (b=n>>9, k=n&511).
// 512 thr = 8 waves (2M x 4N), wave tile 128x64, 16x16x32 MFMA.
// LDS 128KB = 2 dbufs x (A 256x64 | B 256x64); dbuf0 = even K-tiles, dbuf1 = odd.
// Iter it (16 total) computes tiles a=2it (dbuf0, ph1-4) and a+1 (dbuf1, ph5-8).
// Quadrant phases (read-once, frags held in regs):
//   ph1 rd A0+B0 (12 b128), mfma q00; ph2 rd B1 (4), q01; ph3 rd A1 (8), q10;
//   ph4 rd 0, q11; ph5-8 repeat for tile a+1.
// Sliding-window staging, 1 half-tile (=2 gload_lds, 128 rows x 64k) / phase:
//   ph1: A.h0(a+1)  ph2: A.h1(a+1)   [skip it==0: prologue]
//   ph3: B.h0(a+2)  ph4: B.h1(a+2)   [skip last]
//   ph5: A.h0(a+2)  ph6: A.h1(a+2)   [skip last]
//   ph7: B.h0(a+3)  ph8: B.h1(a+3)   [skip last]
// Every stage lands >=2 barriers after its region's last read (audited).
// vmcnt(4) at ph4 & ph8 ONLY (ledger: retires exactly the A+B of the tile
// read in the next phase-group; retired loads are 4-6 phases (~2000cy) old).
// Last iter: ph4 vmcnt(0) (drains ~2000cy-old loads, free), ph8 none.
// Swizzle: LDS slot s holds global chunk s^(row&7); read slot (kh*4+lq)^(lr&7)
// -> 8 lanes per 16B slot = exactly conflict-free; inverse on staging source.
__global__ __launch_bounds__(512, 2) void gemm_ring(
    const u16* __restrict__ A, const u16* __restrict__ Bt,
    float* __restrict__ outF, int M, int N, int K) {
  __shared__ u16 lds[65536];   // 128 KiB: dbuf d at d*32768; B at +16384

  // XCD-chunked swizzle: XCD owns contiguous N-chunk, M fastest inside.
  int nwg = gridDim.x * gridDim.y;
  int wg = blockIdx.y * gridDim.x + blockIdx.x;
  int cpx = nwg >> 3;
  int swz = (wg & 7) * cpx + (wg >> 3);
  int bx = swz & 7, by = swz >> 3;          // gridDim.x == 8
  int m0 = bx * 256, n0 = by * 256;

  int t = threadIdx.x;
  int w = t >> 6, lane = t & 63;
  int wr = w >> 2, wc = w & 3;              // wave tile: 128 rows x 64 cols
  int lr = lane & 15, lq = lane >> 4;
  const int s0 = (lq ^ (lr & 7)) * 8;       // k-half 0 slot offset (u16)
  const int s1 = s0 ^ 32;                   // k-half 1 (chunk ^ 4 -> ^32 u16)

  // staging: thread t covers row (t>>3) of a 64-row call, slot (t&7);
  // source chunk inverse-swizzled (involution).
  int rloc = t >> 3;                                   // 0..63
  int cch = ((t & 7) ^ (rloc & 7)) * 8;
  const u16* pAs = A + (long long)(m0 + rloc) * K + cch;
  const u16* pBs = Bt + (long long)(n0 + rloc) * K + cch;
  const int w512 = w * 512;                            // wave LDS base in call

  f32x4 acc[8][4];
  #pragma unroll
  for (int i = 0; i < 8; ++i)
    #pragma unroll
    for (int j = 0; j < 4; ++j)
      acc[i][j] = (f32x4){0.f, 0.f, 0.f, 0.f};

  // stage one half-tile: OP 0=A 1=B, dbuf D, half H, K-tile KT (2 calls)
  #define STG_H(OP, D, H, KT) do {                                                    \
    const u16* sp_ = (OP) ? pBs : pAs;                                                \
    long long ro_ = (long long)((H) * 128) * K + (long long)(KT) * 64;                \
    int db_ = (D) * 32768 + (OP) * 16384 + (H) * 128 * 64 + w512;                     \
    __builtin_amdgcn_global_load_lds(GCAST(sp_ + ro_),          LCAST(&lds[db_]),        16, 0, 0); \
    __builtin_amdgcn_global_load_lds(GCAST(sp_ + ro_ + 64 * K), LCAST(&lds[db_ + 4096]), 16, 0, 0); \
  } while (0)

  #define RDA(DST, RI, D) {                                                           \
    _Pragma("unroll")                                                                 \
    for (int ii = 0; ii < 4; ++ii) {                                                  \
      int ro_ = (D) * 32768 + (wr * 128 + ((RI) * 4 + ii) * 16 + lr) * 64;            \
      DST[ii * 2]     = *(const short8*)&lds[ro_ + s0];                               \
      DST[ii * 2 + 1] = *(const short8*)&lds[ro_ + s1];                               \
    } }

  #define RDB(DST, CJ, D) {                                                           \
    _Pragma("unroll")                                                                 \
    for (int jj = 0; jj < 2; ++jj) {                                                  \
      int ro_ = (D) * 32768 + 16384 + (wc * 64 + ((CJ) * 2 + jj) * 16 + lr) * 64;     \
      DST[jj * 2]     = *(const short8*)&lds[ro_ + s0];                               \
      DST[jj * 2 + 1] = *(const short8*)&lds[ro_ + s1];                               \
    } }

  #define MFQ(RI, CJ, AF, BF) {                                                       \
    __builtin_amdgcn_s_setprio(1);                                                    \
    _Pragma("unroll")                                                                 \
    for (int ii = 0; ii < 4; ++ii)                                                    \
      _Pragma("unroll")                                                               \
      for (int jj = 0; jj < 2; ++jj)                                                  \
        _Pragma("unroll")                                                             \
        for (int kh = 0; kh < 2; ++kh)                                                \
          acc[(RI) * 4 + ii][(CJ) * 2 + jj] = __builtin_amdgcn_mfma_f32_16x16x32_bf16(\
              AF[ii * 2 + kh], BF[jj * 2 + kh], acc[(RI) * 4 + ii][(CJ) * 2 + jj], 0, 0, 0); \
    __builtin_amdgcn_s_setprio(0); }

  #define SB0 __builtin_amdgcn_sched_barrier(0)
  #define BAR __builtin_amdgcn_s_barrier()
  #define PH_SYNC() do { SB0; BAR;                                                    \
    asm volatile("s_waitcnt lgkmcnt(0)" ::: "memory"); SB0; } while (0)

  short8 a0[8], a1[8], b0[4], b1[4];

  // prologue: tiles 0 -> dbuf0, 1 -> dbuf1 (16 loads); drain; barrier
  STG_H(0, 0, 0, 0); STG_H(0, 0, 1, 0); STG_H(1, 0, 0, 0); STG_H(1, 0, 1, 0);
  STG_H(0, 1, 0, 1); STG_H(0, 1, 1, 1); STG_H(1, 1, 0, 1); STG_H(1, 1, 1, 1);
  asm volatile("s_waitcnt vmcnt(0)" ::: "memory");
  BAR; SB0;

  const int NIT = K >> 7;   // 16 iters (2 K-tiles of 64 each)
  for (int it = 0; it < NIT; ++it) {
    const int a = it * 2;
    const bool first = (it == 0), last = (it == NIT - 1);
    // ---- ph1: rd A0,B0 (tile a, dbuf0); stage A.h0(a+1)->dbuf1
    RDA(a0, 0, 0); RDB(b0, 0, 0);
    if (!first) STG_H(0, 1, 0, a + 1);
    PH_SYNC();
    MFQ(0, 0, a0, b0);
    SB0; BAR;
    // ---- ph2: rd B1; stage A.h1(a+1)
    RDB(b1, 1, 0);
    if (!first) STG_H(0, 1, 1, a + 1);
    PH_SYNC();
    MFQ(0, 1, a0, b1);
    SB0; BAR;
    // ---- ph3: rd A1; stage B.h0(a+2)->dbuf0
    RDA(a1, 1, 0);
    if (!last) STG_H(1, 0, 0, a + 2);
    PH_SYNC();
    MFQ(1, 0, a1, b0);
    SB0; BAR;
    // ---- ph4: no reads; stage B.h1(a+2); vmcnt(4)
    if (!last) STG_H(1, 0, 1, a + 2);
    SB0; BAR; SB0;
    MFQ(1, 1, a1, b1);
    SB0;
    if (!last) { asm volatile("s_waitcnt vmcnt(4)" ::: "memory"); }
    else       { asm volatile("s_waitcnt vmcnt(0)" ::: "memory"); }
    BAR; SB0;
    // ---- ph5: rd A0,B0 (tile a+1, dbuf1); stage A.h0(a+2)->dbuf0
    RDA(a0, 0, 1); RDB(b0, 0, 1);
    if (!last) STG_H(0, 0, 0, a + 2);
    PH_SYNC();
    MFQ(0, 0, a0, b0);
    SB0; BAR;
    // ---- ph6: rd B1; stage A.h1(a+2)
    RDB(b1, 1, 1);
    if (!last) STG_H(0, 0, 1, a + 2);
    PH_SYNC();
    MFQ(0, 1, a0, b1);
    SB0; BAR;
    // ---- ph7: rd A1; stage B.h0(a+3)->dbuf1
    RDA(a1, 1, 1);
    if (!last) STG_H(1, 1, 0, a + 3);
    PH_SYNC();
    MFQ(1, 0, a1, b0);
    SB0; BAR;
    // ---- ph8: no reads; stage B.h1(a+3); vmcnt(4)
    if (!last) STG_H(1, 1, 1, a + 3);
    SB0; BAR; SB0;
    MFQ(1, 1, a1, b1);
    SB0;
    if (!last) { asm volatile("s_waitcnt vmcnt(4)" ::: "memory"); BAR; SB0; }
  }

  #undef STG_H
  #undef RDA
  #undef RDB
  #undef MFQ
  #undef SB0
  #undef BAR
  #undef PH_SYNC

  // epilogue: scatter cols -> per-batch layout
  #pragma unroll
  for (int i = 0; i < 8; ++i) {
    #pragma unroll
    for (int j = 0; j < 4; ++j) {
      int col = n0 + wc * 64 + j * 16 + lr;
      int b = col >> 9, kc = col & 511;
      float* ob = outF + (long long)b * ((long long)M * 512) + kc;
      #pragma unroll
      for (int r = 0; r < 4; ++r) {
        int row = m0 + wr * 128 + i * 16 + lq * 4 + r;
        ob[(long long)row * 512] = acc[i][j][r];
      }
    }
  }
}

// ---- transpose f32 [R][C] -> bf16 [C][R]  (fallback path only)
__global__ __launch_bounds__(256) void transpose_cvt(const float* __restrict__ src,
                                                     u16* __restrict__ dst, int R, int C) {
  __shared__ float tile[32][33];
  int c0 = blockIdx.x * 32, r0 = blockIdx.y * 32;
  int tx = threadIdx.x & 31, ty = threadIdx.x >> 5;
  #pragma unroll
  for (int i = 0; i < 32; i += 8)
    tile[ty + i][tx] = src[(long long)(r0 + ty + i) * C + c0 + tx];
  __syncthreads();
  #pragma unroll
  for (int i = 0; i < 32; i += 8)
    dst[(long long)(c0 + ty + i) * R + r0 + tx] = f2b(tile[tx][ty + i]);
}

// ============ fallback (round-1 kernel) for small-ws path ============
#define BMT 128
#define BNT 128
#define BKT 32
#define LDSP 40

template<int MODE>
__global__ __launch_bounds__(256) void gemm_bt(
    const u16* __restrict__ A, const u16* __restrict__ Bt,
    const float* __restrict__ bias, const float* __restrict__ fixmat,
    float* __restrict__ outF, u16* __restrict__ outB,
    int M, int N, int K, long long out_batch_stride, int bt_batch_stride) {
  __shared__ u16 sA[BMT][LDSP];
  __shared__ u16 sB[BNT][LDSP];
  int b = blockIdx.z;
  const u16* Bt_b = Bt + (long long)b * bt_batch_stride;
  const float* fixrow = (MODE == 2) ? (fixmat + (long long)b * K) : nullptr;
  float* out_b = (MODE == 1 || MODE == 2) ? (outF + (long long)b * out_batch_stride) : nullptr;

  int m0 = blockIdx.y * BMT, n0 = blockIdx.x * BNT;
  int t = threadIdx.x;
  int wid = t >> 6, lane = t & 63;
  int wm = (wid >> 1) * 64, wn = (wid & 1) * 64;
  int lr = lane & 15, lq = lane >> 4;

  f32x4 acc[4][4];
  #pragma unroll
  for (int i = 0; i < 4; ++i)
    #pragma unroll
    for (int j = 0; j < 4; ++j)
      acc[i][j] = (f32x4){0.f, 0.f, 0.f, 0.f};

  int srow = t >> 1, scg = (t & 1) * 16;

  for (int k0 = 0; k0 < K; k0 += BKT) {
    {
      const u16* src = A + (long long)(m0 + srow) * K + k0 + scg;
      short8 v0 = *(const short8*)(src);
      short8 v1 = *(const short8*)(src + 8);
      *(short8*)&sA[srow][scg] = v0;
      *(short8*)&sA[srow][scg + 8] = v1;
    }
    {
      const u16* src = Bt_b + (long long)(n0 + srow) * K + k0 + scg;
      short8 v0 = *(const short8*)(src);
      short8 v1 = *(const short8*)(src + 8);
      if (MODE == 2) {
        u16* p0 = (u16*)&v0; u16* p1 = (u16*)&v1;
        #pragma unroll
        for (int j = 0; j < 8; ++j) {
          p0[j] = f2b(b2f(p0[j]) * fixrow[k0 + scg + j]);
          p1[j] = f2b(b2f(p1[j]) * fixrow[k0 + scg + 8 + j]);
        }
      }
      *(short8*)&sB[srow][scg] = v0;
      *(short8*)&sB[srow][scg + 8] = v1;
    }
    __syncthreads();
    short8 af[4], bf[4];
    #pragma unroll
    for (int i = 0; i < 4; ++i)
      af[i] = *(const short8*)&sA[wm + i * 16 + lr][lq * 8];
    #pragma unroll
    for (int j = 0; j < 4; ++j)
      bf[j] = *(const short8*)&sB[wn + j * 16 + lr][lq * 8];
    #pragma unroll
    for (int i = 0; i < 4; ++i)
      #pragma unroll
      for (int j = 0; j < 4; ++j)
        acc[i][j] = __builtin_amdgcn_mfma_f32_16x16x32_bf16(af[i], bf[j], acc[i][j], 0, 0, 0);
    __syncthreads();
  }

  #pragma unroll
  for (int i = 0; i < 4; ++i) {
    #pragma unroll
    for (int j = 0; j < 4; ++j) {
      int col = n0 + wn + j * 16 + lr;
      #pragma unroll
      for (int r = 0; r < 4; ++r) {
        int row = m0 + wm + i * 16 + lq * 4 + r;
        float v = acc[i][j][r];
        if (MODE == 0) {
          v += bias[col];
          outB[(long long)row * N + col] = f2b(v);
        } else if (MODE == 3) {
          outB[(long long)row * N + col] = f2b(v);
        } else {
          out_b[(long long)row * N + col] = v;
        }
      }
    }
  }
}

extern "C" void kernel_launch(void* const* d_in, const int* in_sizes, int n_in,
                              void* d_out, int out_size, void* d_ws, size_t ws_size,
                              hipStream_t stream) {
  const float* main_feat  = (const float*)d_in[0];
  const float* other_feat = (const float*)d_in[1];
  const float* fix_feat   = (const float*)d_in[2];
  const int*   mask       = (const int*)d_in[3];
  const float* Wq         = (const float*)d_in[4];
  const float* bq         = (const float*)d_in[5];
  const float* Wk         = (const float*)d_in[6];
  const float* bk         = (const float*)d_in[7];
  float* out = (float*)d_out;

  char* ws = (char*)d_ws;
  const size_t OFF_MAINB  = 0;          // 2 MiB (mainB, otherB contiguous)
  const size_t OFF_OTHERB = 2097152;    // 2 MiB
  const size_t OFF_WQB    = 4194304;    // 512 KiB
  const size_t OFF_WKB    = 4718592;    // 512 KiB
  const size_t OFF_QB     = 5242880;    // 2 MiB (QB, KB contiguous)
  const size_t OFF_KB     = 7340032;    // 2 MiB
  const size_t OFF_OTB    = 9437184;    // 2 MiB (fallback only)
  const size_t OFF_P      = 11534336;   // 8 MiB (P bf16 [2048][2048])
  const size_t OFF_S      = 19922944;   // 8 MiB used (S bf16 [2048][2048])
  const size_t OFF_SCALED = 36700160;   // 64 MiB (scaled bf16 [32][512][2048])
  const size_t NEED_SCALED = OFF_SCALED + (size_t)BATCH_ * 512 * 2048 * 2;

  u16* mainB  = (u16*)(ws + OFF_MAINB);
  u16* otherB = (u16*)(ws + OFF_OTHERB);
  u16* WqB    = (u16*)(ws + OFF_WQB);
  u16* WkB    = (u16*)(ws + OFF_WKB);
  u16* QB     = (u16*)(ws + OFF_QB);
  u16* KB     = (u16*)(ws + OFF_KB);
  u16* oTB    = (u16*)(ws + OFF_OTB);
  u16* P      = (u16*)(ws + OFF_P);
  u16* S      = (u16*)(ws + OFF_S);
  u16* scaled = (u16*)(ws + OFF_SCALED);
  bool use_scaled = (ws_size >= NEED_SCALED);

  // 1) bf16 conversions (two dual launches)
  cvt_bf16_dual<<<2048, 256, 0, stream>>>(main_feat, mainB, 2048 * 512,
                                          other_feat, otherB, 2048 * 512);
  cvt_bf16_dual<<<512, 256, 0, stream>>>(Wq, WqB, 512 * 512,
                                         Wk, WkB, 512 * 512);

  if (use_scaled) {
    // 2) fused transpose+scale: scaled[b][k][o]
    transpose_scale<<<dim3(16, 64), 256, 0, stream>>>(other_feat, fix_feat, scaled);
    // 3) fused Q|K projection
    gemm_lds<0><<<dim3(4, 32), 256, 0, stream>>>(mainB, WqB, bq, WkB, bk,
        nullptr, QB, 4096, 512, 512);
    // 4) S = Q @ K^T (bf16 out; softmax applies 1/sqrt(512))
    gemm_lds<3><<<dim3(16, 16), 256, 0, stream>>>(QB, KB, nullptr, nullptr, nullptr,
        nullptr, S, 2048, 2048, 512);
    // 5) masked softmax -> P bf16
    softmax_mask<<<2048, 256, 0, stream>>>(S, mask, P, 2048);
    // 6) 8-phase sliding-window GEMM: out[b][m][k] via col scatter
    gemm_ring<<<dim3(8, 64), 512, 0, stream>>>(P, scaled, out, 2048, 16384, 2048);
  } else {
    // fallback: no 64MB scaled buffer
    transpose_cvt<<<dim3(16, 64), 256, 0, stream>>>(other_feat, oTB, 2048, 512);
    gemm_bt<0><<<dim3(4, 16, 1), 256, 0, stream>>>(mainB, WqB, bq, nullptr,
        nullptr, QB, 2048, 512, 512, 0, 0);
    gemm_bt<0><<<dim3(4, 16, 1), 256, 0, stream>>>(otherB, WkB, bk, nullptr,
        nullptr, KB, 2048, 512, 512, 0, 0);
    gemm_bt<3><<<dim3(16, 16, 1), 256, 0, stream>>>(QB, KB, nullptr, nullptr,
        nullptr, S, 2048, 2048, 512, 0, 0);
    softmax_mask<<<2048, 256, 0, stream>>>(S, mask, P, 2048);
    gemm_bt<2><<<dim3(4, 16, BATCH_), 256, 0, stream>>>(P, oTB, nullptr, fix_feat,
        out, nullptr, 2048, 512, 2048, 1048576LL, 0);
  }
}

// Round 16
// 176.396 us; speedup vs baseline: 1.0049x; 1.0049x over previous
//
#include <hip/hip_runtime.h>
#include <hip/hip_bf16.h>

typedef unsigned short u16;
typedef __attribute__((ext_vector_type(8))) short short8;
typedef __attribute__((ext_vector_type(4))) float f32x4;

#define BATCH_ 32

static __device__ __forceinline__ float b2f(u16 u) {
  union { unsigned int i; float f; } v; v.i = ((unsigned int)u) << 16; return v.f;
}
static __device__ __forceinline__ u16 f2b(float x) {
  unsigned int i = __float_as_uint(x);
  unsigned int r = (i + 0x7fffu + ((i >> 16) & 1u)) >> 16;
  return (u16)r;
}

#define GCAST(p) ((const __attribute__((address_space(1))) void*)(p))
#define LCAST(p) ((__attribute__((address_space(3))) void*)(p))

// ---- dual-source f32 -> bf16 (n1, n2 % 4 == 0); one launch for two arrays
__global__ __launch_bounds__(256) void cvt_bf16_dual(
    const float* __restrict__ s1, u16* __restrict__ d1, int n1,
    const float* __restrict__ s2, u16* __restrict__ d2, int n2) {
  int i = (blockIdx.x * 256 + threadIdx.x) * 4;
  const float* s; u16* d; int idx;
  if (i < n1) { s = s1; d = d1; idx = i; }
  else { idx = i - n1; if (idx >= n2) return; s = s2; d = d2; }
  float4 v = *(const float4*)(s + idx);
  ushort4 o;
  o.x = f2b(v.x); o.y = f2b(v.y); o.z = f2b(v.z); o.w = f2b(v.w);
  *(ushort4*)(d + idx) = o;
}

// ---- fused transpose+scale: scaled[b][k][o] = other[o][k] * fix[b][o]
__global__ __launch_bounds__(256) void transpose_scale(
    const float* __restrict__ other, const float* __restrict__ fix,
    u16* __restrict__ scaled) {
  __shared__ float tile[32][33];   // [o_local][k_local]
  __shared__ float fixs[32][33];   // [b][o_local]
  int k0 = blockIdx.x * 32, o0 = blockIdx.y * 32;
  int tx = threadIdx.x & 31, ty = threadIdx.x >> 5;   // ty 0..7
  #pragma unroll
  for (int i = 0; i < 32; i += 8)
    tile[ty + i][tx] = other[(long long)(o0 + ty + i) * 512 + k0 + tx];
  #pragma unroll
  for (int i = 0; i < 32; i += 8)
    fixs[ty + i][tx] = fix[(long long)(ty + i) * 2048 + o0 + tx];
  __syncthreads();
  int kk = threadIdx.x >> 4;          // 0..15
  int oo = (threadIdx.x & 15) * 2;    // 0,2,..30
  #pragma unroll 4
  for (int b = 0; b < 32; ++b) {
    #pragma unroll
    for (int p = 0; p < 2; ++p) {
      int k = kk + p * 16;
      ushort2 w;
      w.x = f2b(tile[oo][k] * fixs[b][oo]);
      w.y = f2b(tile[oo + 1][k] * fixs[b][oo + 1]);
      *(ushort2*)(scaled + ((long long)(b * 512 + k0 + k) * 2048 + o0 + oo)) = w;
    }
  }
}

// ---- masked row softmax on bf16 S, vectorized I/O (8 contiguous elems/thr)
__global__ __launch_bounds__(256) void softmax_mask(const u16* __restrict__ S,
                                                    const int* __restrict__ mask,
                                                    u16* __restrict__ P, int N) {
  const float scale = 0.044194173824159216f; // 1/sqrt(512)
  int row = blockIdx.x;
  int t = threadIdx.x;
  long long base = (long long)row * N + t * 8;
  short8 sv = *(const short8*)(S + base);
  int4 m0 = *(const int4*)(mask + base);
  int4 m1 = *(const int4*)(mask + base + 4);
  int msk[8] = {m0.x, m0.y, m0.z, m0.w, m1.x, m1.y, m1.z, m1.w};
  float vals[8];
  float mx = -3.0e38f;
  #pragma unroll
  for (int i = 0; i < 8; ++i) {
    vals[i] = b2f((u16)sv[i]) * scale;
    if (!msk[i]) mx = fmaxf(mx, vals[i]);
  }
  #pragma unroll
  for (int off = 32; off; off >>= 1) mx = fmaxf(mx, __shfl_xor(mx, off));
  __shared__ float sred[4];
  if ((t & 63) == 0) sred[t >> 6] = mx;
  __syncthreads();
  mx = fmaxf(fmaxf(sred[0], sred[1]), fmaxf(sred[2], sred[3]));
  __syncthreads();
  float e[8]; float sum = 0.f;
  #pragma unroll
  for (int i = 0; i < 8; ++i) {
    e[i] = msk[i] ? 0.f : __expf(vals[i] - mx);
    sum += e[i];
  }
  #pragma unroll
  for (int off = 32; off; off >>= 1) sum += __shfl_xor(sum, off);
  if ((t & 63) == 0) sred[t >> 6] = sum;
  __syncthreads();
  sum = sred[0] + sred[1] + sred[2] + sred[3];
  float inv = (sum > 0.f) ? (1.f / sum) : 0.f;
  short8 ov;
  #pragma unroll
  for (int i = 0; i < 8; ++i) ov[i] = (short)f2b(e[i] * inv);
  *(short8*)(P + base) = ov;
}

// ========== r2-proven 128x128 / BK=32 GEMM (small GEMMs: Q|K proj, S) ======
// EPI 0: outB = bf16(C + bias[col]); dual-weight via second half of grid.y
// EPI 1: outF = C (f32)
// EPI 3: outB = bf16(C)           (bf16 S output)
#define GBM 128
#define GBN 128
#define GBK 32

template<int EPI>
__global__ __launch_bounds__(256) void gemm_lds(
    const u16* __restrict__ A, const u16* __restrict__ Bt,
    const float* __restrict__ bias,
    const u16* __restrict__ Bt2, const float* __restrict__ bias2,
    float* __restrict__ outF, u16* __restrict__ outB,
    int M, int N, int K) {
  __shared__ u16 sA[GBM * GBK];
  __shared__ u16 sB[GBN * GBK];
  int m0 = blockIdx.y * GBM, n0 = blockIdx.x * GBN;
  if (EPI == 0) {
    if (2 * blockIdx.y >= gridDim.y) { Bt = Bt2; bias = bias2; }
  }
  int t = threadIdx.x;
  int wid = t >> 6, lane = t & 63;
  int wm = (wid >> 1) * 64, wn = (wid & 1) * 64;
  int lr = lane & 15, lq = lane >> 4;
  int srow = lane >> 2, schunk = (lane & 3) * 8;

  f32x4 acc[4][4];
  #pragma unroll
  for (int i = 0; i < 4; ++i)
    #pragma unroll
    for (int j = 0; j < 4; ++j)
      acc[i][j] = (f32x4){0.f, 0.f, 0.f, 0.f};

  const u16* gA = A + (long long)(m0 + wid * 32 + srow) * K + schunk;
  const u16* gB = Bt + (long long)(n0 + wid * 32 + srow) * K + schunk;
  u16* lA = &sA[(wid * 32) * GBK];
  u16* lB = &sB[(wid * 32) * GBK];
  const long long rowskip = (long long)16 * K;

  for (int k0 = 0; k0 < K; k0 += GBK) {
    __builtin_amdgcn_global_load_lds(GCAST(gA + k0),           LCAST(lA),            16, 0, 0);
    __builtin_amdgcn_global_load_lds(GCAST(gA + k0 + rowskip), LCAST(lA + 16 * GBK), 16, 0, 0);
    __builtin_amdgcn_global_load_lds(GCAST(gB + k0),           LCAST(lB),            16, 0, 0);
    __builtin_amdgcn_global_load_lds(GCAST(gB + k0 + rowskip), LCAST(lB + 16 * GBK), 16, 0, 0);
    __syncthreads();
    short8 af[4], bf[4];
    #pragma unroll
    for (int i = 0; i < 4; ++i)
      af[i] = *(const short8*)&sA[(wm + i * 16 + lr) * GBK + lq * 8];
    #pragma unroll
    for (int j = 0; j < 4; ++j)
      bf[j] = *(const short8*)&sB[(wn + j * 16 + lr) * GBK + lq * 8];
    #pragma unroll
    for (int i = 0; i < 4; ++i)
      #pragma unroll
      for (int j = 0; j < 4; ++j)
        acc[i][j] = __builtin_amdgcn_mfma_f32_16x16x32_bf16(af[i], bf[j], acc[i][j], 0, 0, 0);
    __syncthreads();
  }

  #pragma unroll
  for (int i = 0; i < 4; ++i) {
    #pragma unroll
    for (int j = 0; j < 4; ++j) {
      int col = n0 + wn + j * 16 + lr;
      #pragma unroll
      for (int r = 0; r < 4; ++r) {
        int row = m0 + wm + i * 16 + lq * 4 + r;
        float v = acc[i][j][r];
        if (EPI == 0) {
          outB[(long long)row * N + col] = f2b(v + bias[col]);
        } else if (EPI == 1) {
          outF[(long long)row * N + col] = v;
        } else {
          outB[(long long)row * N + col] = f2b(v);
        }
      }
    }
  }
}

// ========== ring-4 counted-vmcnt 256x256 GEMM + reg prefetch + SGB =========
// R7-verbatim (benched 136-137.5us, MfmaUtil 45.5%, 0 conflicts). Converged:
// 8-phase ports (R8/R10/R15), 32x32 shape (R9), no-LDS (R12), smaller tiles
// (R13) and occupancy plays (R11) all measured slower on this problem.
#define SGB __builtin_amdgcn_sched_group_barrier
// masks: MFMA=0x008, VMEM_READ=0x020, DS_READ=0x100

__global__ __launch_bounds__(512, 2) void gemm_ring(
    const u16* __restrict__ A, const u16* __restrict__ Bt,
    float* __restrict__ outF, int M, int N, int K) {
  __shared__ u16 lds[4][2][8192];   // [ring][A/B][row*32 + slot*8] = 128 KiB

  // XCD-chunked swizzle: XCD owns contiguous N-chunk, M fastest inside.
  int nwg = gridDim.x * gridDim.y;
  int wg = blockIdx.y * gridDim.x + blockIdx.x;
  int cpx = nwg >> 3;
  int swz = (wg & 7) * cpx + (wg >> 3);
  int bx = swz & 7, by = swz >> 3;          // gridDim.x == 8
  int m0 = bx * 256, n0 = by * 256;

  int t = threadIdx.x;
  int w = t >> 6, lane = t & 63;
  int wr = w >> 2, wc = w & 3;              // wave tile: 128 rows x 64 cols
  int lr = lane & 15, lq = lane >> 4;
  int csw = (((lr >> 1) & 3) ^ lq) * 8;     // swizzled slot offset (u16)

  // staging source (pre-swizzled): thread t covers row (t>>2), slot (t&3)
  int srow = t >> 2;                                  // 0..127
  int sgc = (((srow >> 1) & 3) ^ (t & 3)) * 8;        // inverse-swizzled chunk
  const u16* pA0 = A + (long long)(m0 + srow) * K + sgc;
  const u16* pA1 = pA0 + (long long)128 * K;
  const u16* pB0 = Bt + (long long)(n0 + srow) * K + sgc;
  const u16* pB1 = pB0 + (long long)128 * K;
  const int lbase = (w * 16) * 32;           // wave-uniform LDS base (u16)

  f32x4 acc[8][4];
  #pragma unroll
  for (int i = 0; i < 8; ++i)
    #pragma unroll
    for (int j = 0; j < 4; ++j)
      acc[i][j] = (f32x4){0.f, 0.f, 0.f, 0.f};

  const int NT = K >> 5;   // K/32 tiles (=64)

  #define STAGE_TILE(KT, SB)                                                          \
    do {                                                                              \
      long long cofs = (long long)(KT) * 32;                                          \
      __builtin_amdgcn_global_load_lds(GCAST(pA0 + cofs), LCAST(&lds[SB][0][lbase]),            16, 0, 0); \
      __builtin_amdgcn_global_load_lds(GCAST(pA1 + cofs), LCAST(&lds[SB][0][lbase + 128 * 32]), 16, 0, 0); \
      __builtin_amdgcn_global_load_lds(GCAST(pB0 + cofs), LCAST(&lds[SB][1][lbase]),            16, 0, 0); \
      __builtin_amdgcn_global_load_lds(GCAST(pB1 + cofs), LCAST(&lds[SB][1][lbase + 128 * 32]), 16, 0, 0); \
    } while (0)

  #define RD_FRAGS(AF, BF, BUF) {                                                     \
    _Pragma("unroll")                                                                 \
    for (int i = 0; i < 8; ++i)                                                       \
      AF[i] = *(const short8*)&lds[BUF][0][(wr * 128 + i * 16 + lr) * 32 + csw];      \
    _Pragma("unroll")                                                                 \
    for (int j = 0; j < 4; ++j)                                                       \
      BF[j] = *(const short8*)&lds[BUF][1][(wc * 64 + j * 16 + lr) * 32 + csw]; }

  #define MFMA_NP(AF, BF) {                                                           \
    _Pragma("unroll")                                                                 \
    for (int i = 0; i < 8; ++i)                                                       \
      _Pragma("unroll")                                                               \
      for (int j = 0; j < 4; ++j)                                                     \
        acc[i][j] = __builtin_amdgcn_mfma_f32_16x16x32_bf16(AF[i], BF[j], acc[i][j], 0, 0, 0); }

  #define MFMA_BLK(AF, BF) {                                                          \
    __builtin_amdgcn_s_setprio(1);                                                    \
    MFMA_NP(AF, BF);                                                                  \
    __builtin_amdgcn_s_setprio(0); }

  // issue-interleave directive tail: {MFMA2} {DS2,MFMA4}x3 {VMEM4} {DS2,MFMA4}x3 {MFMA6}
  #define SGB_TAIL() {                                                                \
    SGB(0x008, 2, 0);                                                                 \
    SGB(0x100, 2, 0); SGB(0x008, 4, 0);                                               \
    SGB(0x100, 2, 0); SGB(0x008, 4, 0);                                               \
    SGB(0x100, 2, 0); SGB(0x008, 4, 0);                                               \
    SGB(0x020, 4, 0);                                                                 \
    SGB(0x100, 2, 0); SGB(0x008, 4, 0);                                               \
    SGB(0x100, 2, 0); SGB(0x008, 4, 0);                                               \
    SGB(0x100, 2, 0); SGB(0x008, 4, 0);                                               \
    SGB(0x008, 6, 0); }

  short8 afA[8], bfA[4], afB[8], bfB[4];

  // prologue: stage tiles 0,1,2 (12 loads); vmcnt(4) -> tiles 0,1 resident
  STAGE_TILE(0, 0);
  STAGE_TILE(1, 1);
  STAGE_TILE(2, 2);
  asm volatile("s_waitcnt vmcnt(4)" ::: "memory");
  __builtin_amdgcn_s_barrier();
  __builtin_amdgcn_sched_barrier(0);
  RD_FRAGS(afA, bfA, 0);                     // regs <- tile 0

  // steady state: 2 iters per body; invariant at iter kt entry:
  //   tiles <= kt+1 LDS-resident, tile kt+2's 4 loads outstanding.
  for (int kt = 0; kt + 4 < NT; kt += 2) {
    // ---- iter kt (cur = A)
    RD_FRAGS(afB, bfB, ((kt + 1) & 3));      // regs <- tile kt+1 (resident)
    STAGE_TILE(kt + 3, ((kt + 3) & 3));      // outstanding: kt+2, kt+3 (8)
    MFMA_NP(afA, bfA);                       // tile kt; interleaved via SGB
    SGB_TAIL();
    asm volatile("s_waitcnt vmcnt(4)" ::: "memory");   // tile kt+2 resident
    __builtin_amdgcn_s_barrier();
    __builtin_amdgcn_sched_barrier(0);
    // ---- iter kt+1 (cur = B)
    RD_FRAGS(afA, bfA, ((kt + 2) & 3));
    STAGE_TILE(kt + 4, ((kt + 4) & 3));
    MFMA_NP(afB, bfB);
    SGB_TAIL();
    asm volatile("s_waitcnt vmcnt(4)" ::: "memory");
    __builtin_amdgcn_s_barrier();
    __builtin_amdgcn_sched_barrier(0);
  }

  // tail: iters NT-4 .. NT-1 (steady loop ended at iter NT-5, parity even)
  // iter NT-4 (cur = A)
  RD_FRAGS(afB, bfB, ((NT - 3) & 3));
  STAGE_TILE(NT - 1, ((NT - 1) & 3));
  __builtin_amdgcn_sched_barrier(0);
  MFMA_BLK(afA, bfA);
  __builtin_amdgcn_sched_barrier(0);
  asm volatile("s_waitcnt vmcnt(4)" ::: "memory");     // tile NT-2 resident
  __builtin_amdgcn_s_barrier();
  __builtin_amdgcn_sched_barrier(0);
  // iter NT-3 (cur = B)
  RD_FRAGS(afA, bfA, ((NT - 2) & 3));
  __builtin_amdgcn_sched_barrier(0);
  MFMA_BLK(afB, bfB);
  __builtin_amdgcn_sched_barrier(0);
  asm volatile("s_waitcnt vmcnt(0)" ::: "memory");     // tile NT-1 resident
  __builtin_amdgcn_s_barrier();
  __builtin_amdgcn_sched_barrier(0);
  // iter NT-2 (cur = A)
  RD_FRAGS(afB, bfB, ((NT - 1) & 3));
  __builtin_amdgcn_sched_barrier(0);
  MFMA_BLK(afA, bfA);
  // iter NT-1 (cur = B) -- pure register MFMA, no barrier needed
  MFMA_BLK(afB, bfB);

  #undef STAGE_TILE
  #undef RD_FRAGS
  #undef MFMA_NP
  #undef MFMA_BLK
  #undef SGB_TAIL

  // epilogue: scatter cols -> per-batch layout
  #pragma unroll
  for (int i = 0; i < 8; ++i) {
    #pragma unroll
    for (int j = 0; j < 4; ++j) {
      int col = n0 + wc * 64 + j * 16 + lr;
      int b = col >> 9, kc = col & 511;
      float* ob = outF + (long long)b * ((long long)M * 512) + kc;
      #pragma unroll
      for (int r = 0; r < 4; ++r) {
        int row = m0 + wr * 128 + i * 16 + lq * 4 + r;
        ob[(long long)row * 512] = acc[i][j][r];
      }
    }
  }
}

// ---- transpose f32 [R][C] -> bf16 [C][R]  (fallback path only)
__global__ __launch_bounds__(256) void transpose_cvt(const float* __restrict__ src,
                                                     u16* __restrict__ dst, int R, int C) {
  __shared__ float tile[32][33];
  int c0 = blockIdx.x * 32, r0 = blockIdx.y * 32;
  int tx = threadIdx.x & 31, ty = threadIdx.x >> 5;
  #pragma unroll
  for (int i = 0; i < 32; i += 8)
    tile[ty + i][tx] = src[(long long)(r0 + ty + i) * C + c0 + tx];
  __syncthreads();
  #pragma unroll
  for (int i = 0; i < 32; i += 8)
    dst[(long long)(c0 + ty + i) * R + r0 + tx] = f2b(tile[tx][ty + i]);
}

// ============ fallback (round-1 kernel) for small-ws path ============
#define BMT 128
#define BNT 128
#define BKT 32
#define LDSP 40

template<int MODE>
__global__ __launch_bounds__(256) void gemm_bt(
    const u16* __restrict__ A, const u16* __restrict__ Bt,
    const float* __restrict__ bias, const float* __restrict__ fixmat,
    float* __restrict__ outF, u16* __restrict__ outB,
    int M, int N, int K, long long out_batch_stride, int bt_batch_stride) {
  __shared__ u16 sA[BMT][LDSP];
  __shared__ u16 sB[BNT][LDSP];
  int b = blockIdx.z;
  const u16* Bt_b = Bt + (long long)b * bt_batch_stride;
  const float* fixrow = (MODE == 2) ? (fixmat + (long long)b * K) : nullptr;
  float* out_b = (MODE == 1 || MODE == 2) ? (outF + (long long)b * out_batch_stride) : nullptr;

  int m0 = blockIdx.y * BMT, n0 = blockIdx.x * BNT;
  int t = threadIdx.x;
  int wid = t >> 6, lane = t & 63;
  int wm = (wid >> 1) * 64, wn = (wid & 1) * 64;
  int lr = lane & 15, lq = lane >> 4;

  f32x4 acc[4][4];
  #pragma unroll
  for (int i = 0; i < 4; ++i)
    #pragma unroll
    for (int j = 0; j < 4; ++j)
      acc[i][j] = (f32x4){0.f, 0.f, 0.f, 0.f};

  int srow = t >> 1, scg = (t & 1) * 16;

  for (int k0 = 0; k0 < K; k0 += BKT) {
    {
      const u16* src = A + (long long)(m0 + srow) * K + k0 + scg;
      short8 v0 = *(const short8*)(src);
      short8 v1 = *(const short8*)(src + 8);
      *(short8*)&sA[srow][scg] = v0;
      *(short8*)&sA[srow][scg + 8] = v1;
    }
    {
      const u16* src = Bt_b + (long long)(n0 + srow) * K + k0 + scg;
      short8 v0 = *(const short8*)(src);
      short8 v1 = *(const short8*)(src + 8);
      if (MODE == 2) {
        u16* p0 = (u16*)&v0; u16* p1 = (u16*)&v1;
        #pragma unroll
        for (int j = 0; j < 8; ++j) {
          p0[j] = f2b(b2f(p0[j]) * fixrow[k0 + scg + j]);
          p1[j] = f2b(b2f(p1[j]) * fixrow[k0 + scg + 8 + j]);
        }
      }
      *(short8*)&sB[srow][scg] = v0;
      *(short8*)&sB[srow][scg + 8] = v1;
    }
    __syncthreads();
    short8 af[4], bf[4];
    #pragma unroll
    for (int i = 0; i < 4; ++i)
      af[i] = *(const short8*)&sA[wm + i * 16 + lr][lq * 8];
    #pragma unroll
    for (int j = 0; j < 4; ++j)
      bf[j] = *(const short8*)&sB[wn + j * 16 + lr][lq * 8];
    #pragma unroll
    for (int i = 0; i < 4; ++i)
      #pragma unroll
      for (int j = 0; j < 4; ++j)
        acc[i][j] = __builtin_amdgcn_mfma_f32_16x16x32_bf16(af[i], bf[j], acc[i][j], 0, 0, 0);
    __syncthreads();
  }

  #pragma unroll
  for (int i = 0; i < 4; ++i) {
    #pragma unroll
    for (int j = 0; j < 4; ++j) {
      int col = n0 + wn + j * 16 + lr;
      #pragma unroll
      for (int r = 0; r < 4; ++r) {
        int row = m0 + wm + i * 16 + lq * 4 + r;
        float v = acc[i][j][r];
        if (MODE == 0) {
          v += bias[col];
          outB[(long long)row * N + col] = f2b(v);
        } else if (MODE == 3) {
          outB[(long long)row * N + col] = f2b(v);
        } else {
          out_b[(long long)row * N + col] = v;
        }
      }
    }
  }
}

extern "C" void kernel_launch(void* const* d_in, const int* in_sizes, int n_in,
                              void* d_out, int out_size, void* d_ws, size_t ws_size,
                              hipStream_t stream) {
  const float* main_feat  = (const float*)d_in[0];
  const float* other_feat = (const float*)d_in[1];
  const float* fix_feat   = (const float*)d_in[2];
  const int*   mask       = (const int*)d_in[3];
  const float* Wq         = (const float*)d_in[4];
  const float* bq         = (const float*)d_in[5];
  const float* Wk         = (const float*)d_in[6];
  const float* bk         = (const float*)d_in[7];
  float* out = (float*)d_out;

  char* ws = (char*)d_ws;
  const size_t OFF_MAINB  = 0;          // 2 MiB (mainB, otherB contiguous)
  const size_t OFF_OTHERB = 2097152;    // 2 MiB
  const size_t OFF_WQB    = 4194304;    // 512 KiB
  const size_t OFF_WKB    = 4718592;    // 512 KiB
  const size_t OFF_QB     = 5242880;    // 2 MiB (QB, KB contiguous)
  const size_t OFF_KB     = 7340032;    // 2 MiB
  const size_t OFF_OTB    = 9437184;    // 2 MiB (fallback only)
  const size_t OFF_P      = 11534336;   // 8 MiB (P bf16 [2048][2048])
  const size_t OFF_S      = 19922944;   // 8 MiB used (S bf16 [2048][2048])
  const size_t OFF_SCALED = 36700160;   // 64 MiB (scaled bf16 [32][512][2048])
  const size_t NEED_SCALED = OFF_SCALED + (size_t)BATCH_ * 512 * 2048 * 2;

  u16* mainB  = (u16*)(ws + OFF_MAINB);
  u16* otherB = (u16*)(ws + OFF_OTHERB);
  u16* WqB    = (u16*)(ws + OFF_WQB);
  u16* WkB    = (u16*)(ws + OFF_WKB);
  u16* QB     = (u16*)(ws + OFF_QB);
  u16* KB     = (u16*)(ws + OFF_KB);
  u16* oTB    = (u16*)(ws + OFF_OTB);
  u16* P      = (u16*)(ws + OFF_P);
  u16* S      = (u16*)(ws + OFF_S);
  u16* scaled = (u16*)(ws + OFF_SCALED);
  bool use_scaled = (ws_size >= NEED_SCALED);

  // 1) bf16 conversions (two dual launches)
  cvt_bf16_dual<<<2048, 256, 0, stream>>>(main_feat, mainB, 2048 * 512,
                                          other_feat, otherB, 2048 * 512);
  cvt_bf16_dual<<<512, 256, 0, stream>>>(Wq, WqB, 512 * 512,
                                         Wk, WkB, 512 * 512);

  if (use_scaled) {
    // 2) fused transpose+scale: scaled[b][k][o]
    transpose_scale<<<dim3(16, 64), 256, 0, stream>>>(other_feat, fix_feat, scaled);
    // 3) fused Q|K projection: M=4096 (rows 0..2047 -> Wq/bq, 2048.. -> Wk/bk)
    gemm_lds<0><<<dim3(4, 32), 256, 0, stream>>>(mainB, WqB, bq, WkB, bk,
        nullptr, QB, 4096, 512, 512);
    // 4) S = Q @ K^T (bf16 out; softmax applies 1/sqrt(512))
    gemm_lds<3><<<dim3(16, 16), 256, 0, stream>>>(QB, KB, nullptr, nullptr, nullptr,
        nullptr, S, 2048, 2048, 512);
    // 5) masked softmax -> P bf16
    softmax_mask<<<2048, 256, 0, stream>>>(S, mask, P, 2048);
    // 6) ring-4 pipelined GEMM (R7): out[b][m][k] via col scatter
    gemm_ring<<<dim3(8, 64), 512, 0, stream>>>(P, scaled, out, 2048, 16384, 2048);
  } else {
    // fallback: no 64MB scaled buffer
    transpose_cvt<<<dim3(16, 64), 256, 0, stream>>>(other_feat, oTB, 2048, 512);
    gemm_bt<0><<<dim3(4, 16, 1), 256, 0, stream>>>(mainB, WqB, bq, nullptr,
        nullptr, QB, 2048, 512, 512, 0, 0);
    gemm_bt<0><<<dim3(4, 16, 1), 256, 0, stream>>>(otherB, WkB, bk, nullptr,
        nullptr, KB, 2048, 512, 512, 0, 0);
    gemm_bt<3><<<dim3(16, 16, 1), 256, 0, stream>>>(QB, KB, nullptr, nullptr,
        nullptr, S, 2048, 2048, 512, 0, 0);
    softmax_mask<<<2048, 256, 0, stream>>>(S, mask, P, 2048);
    gemm_bt<2><<<dim3(4, 16, BATCH_), 256, 0, stream>>>(P, oTB, nullptr, fix_feat,
        out, nullptr, 2048, 512, 2048, 1048576LL, 0);
  }
}

// Round 17
// 173.159 us; speedup vs baseline: 1.0237x; 1.0187x over previous
//
#include <hip/hip_runtime.h>
#include <hip/hip_bf16.h>

typedef unsigned short u16;
typedef __attribute__((ext_vector_type(8))) short short8;
typedef __attribute__((ext_vector_type(4))) float f32x4;

#define BATCH_ 32

static __device__ __forceinline__ float b2f(u16 u) {
  union { unsigned int i; float f; } v; v.i = ((unsigned int)u) << 16; return v.f;
}
static __device__ __forceinline__ u16 f2b(float x) {
  unsigned int i = __float_as_uint(x);
  unsigned int r = (i + 0x7fffu + ((i >> 16) & 1u)) >> 16;
  return (u16)r;
}

#define GCAST(p) ((const __attribute__((address_space(1))) void*)(p))
#define LCAST(p) ((__attribute__((address_space(3))) void*)(p))

// ---- dual-source f32 -> bf16 (n1, n2 % 4 == 0); one launch for two arrays
__global__ __launch_bounds__(256) void cvt_bf16_dual(
    const float* __restrict__ s1, u16* __restrict__ d1, int n1,
    const float* __restrict__ s2, u16* __restrict__ d2, int n2) {
  int i = (blockIdx.x * 256 + threadIdx.x) * 4;
  const float* s; u16* d; int idx;
  if (i < n1) { s = s1; d = d1; idx = i; }
  else { idx = i - n1; if (idx >= n2) return; s = s2; d = d2; }
  float4 v = *(const float4*)(s + idx);
  ushort4 o;
  o.x = f2b(v.x); o.y = f2b(v.y); o.z = f2b(v.z); o.w = f2b(v.w);
  *(ushort4*)(d + idx) = o;
}

// ---- fused transpose+scale: scaled[b][k][o] = other[o][k] * fix[b][o]
// other f32 [2048][512], fix f32 [32][2048], scaled bf16 [32*512][2048].
// 32(o) x 32(k) tile; each thread stores short8 (16B): lane->(og=t&3,
// k=(t>>2)&15, kh=t>>6); 4 adjacent lanes = contiguous 64B segment.
__global__ __launch_bounds__(256) void transpose_scale(
    const float* __restrict__ other, const float* __restrict__ fix,
    u16* __restrict__ scaled) {
  __shared__ float tile[32][33];   // [o_local][k_local]
  __shared__ float fixs[32][33];   // [b][o_local]
  int k0 = blockIdx.x * 32, o0 = blockIdx.y * 32;
  int tx = threadIdx.x & 31, ty = threadIdx.x >> 5;   // ty 0..7
  #pragma unroll
  for (int i = 0; i < 32; i += 8)
    tile[ty + i][tx] = other[(long long)(o0 + ty + i) * 512 + k0 + tx];
  #pragma unroll
  for (int i = 0; i < 32; i += 8)
    fixs[ty + i][tx] = fix[(long long)(ty + i) * 2048 + o0 + tx];
  __syncthreads();
  int og = (threadIdx.x & 3) * 8;              // o-group base: 0,8,16,24
  int k  = (threadIdx.x >> 2) & 15;            // k within half
  int kh = threadIdx.x >> 6;                   // 0..3 -> k half/quarters
  k += kh * 16 & 16;                           // kh 0,1 -> +0; 2,3 -> +16
  int bh = (threadIdx.x >> 6) & 1;             // batch half select (0/1)
  // threads 0-63: kh=0 -> k 0-15, bh 0; 64-127: k 0-15? Fix mapping:
  // use kh bit1 for k-half, bit0 for batch-half:
  k = ((threadIdx.x >> 2) & 15) + ((threadIdx.x >> 7) << 4);  // +16 if t>=128
  bh = (threadIdx.x >> 6) & 1;                                // batch half
  #pragma unroll
  for (int bb = 0; bb < 16; ++bb) {
    int b = bh * 16 + bb;
    short8 w;
    #pragma unroll
    for (int i = 0; i < 8; ++i)
      w[i] = (short)f2b(tile[og + i][k] * fixs[b][og + i]);
    *(short8*)(scaled + ((long long)(b * 512 + k0 + k) * 2048 + o0 + og)) = w;
  }
}

// ---- masked row softmax on bf16 S, vectorized I/O (8 contiguous elems/thr)
__global__ __launch_bounds__(256) void softmax_mask(const u16* __restrict__ S,
                                                    const int* __restrict__ mask,
                                                    u16* __restrict__ P, int N) {
  const float scale = 0.044194173824159216f; // 1/sqrt(512)
  int row = blockIdx.x;
  int t = threadIdx.x;
  long long base = (long long)row * N + t * 8;
  short8 sv = *(const short8*)(S + base);
  int4 m0 = *(const int4*)(mask + base);
  int4 m1 = *(const int4*)(mask + base + 4);
  int msk[8] = {m0.x, m0.y, m0.z, m0.w, m1.x, m1.y, m1.z, m1.w};
  float vals[8];
  float mx = -3.0e38f;
  #pragma unroll
  for (int i = 0; i < 8; ++i) {
    vals[i] = b2f((u16)sv[i]) * scale;
    if (!msk[i]) mx = fmaxf(mx, vals[i]);
  }
  #pragma unroll
  for (int off = 32; off; off >>= 1) mx = fmaxf(mx, __shfl_xor(mx, off));
  __shared__ float sred[4];
  if ((t & 63) == 0) sred[t >> 6] = mx;
  __syncthreads();
  mx = fmaxf(fmaxf(sred[0], sred[1]), fmaxf(sred[2], sred[3]));
  __syncthreads();
  float e[8]; float sum = 0.f;
  #pragma unroll
  for (int i = 0; i < 8; ++i) {
    e[i] = msk[i] ? 0.f : __expf(vals[i] - mx);
    sum += e[i];
  }
  #pragma unroll
  for (int off = 32; off; off >>= 1) sum += __shfl_xor(sum, off);
  if ((t & 63) == 0) sred[t >> 6] = sum;
  __syncthreads();
  sum = sred[0] + sred[1] + sred[2] + sred[3];
  float inv = (sum > 0.f) ? (1.f / sum) : 0.f;
  short8 ov;
  #pragma unroll
  for (int i = 0; i < 8; ++i) ov[i] = (short)f2b(e[i] * inv);
  *(short8*)(P + base) = ov;
}

// ========== r2-proven 128x128 / BK=32 GEMM (small GEMMs: Q|K proj, S) ======
// EPI 0: outB = bf16(C + bias[col]); dual-weight via second half of grid.y
// EPI 1: outF = C (f32)
// EPI 3: outB = bf16(C)           (bf16 S output)
#define GBM 128
#define GBN 128
#define GBK 32

template<int EPI>
__global__ __launch_bounds__(256) void gemm_lds(
    const u16* __restrict__ A, const u16* __restrict__ Bt,
    const float* __restrict__ bias,
    const u16* __restrict__ Bt2, const float* __restrict__ bias2,
    float* __restrict__ outF, u16* __restrict__ outB,
    int M, int N, int K) {
  __shared__ u16 sA[GBM * GBK];
  __shared__ u16 sB[GBN * GBK];
  int m0 = blockIdx.y * GBM, n0 = blockIdx.x * GBN;
  if (EPI == 0) {
    if (2 * blockIdx.y >= gridDim.y) { Bt = Bt2; bias = bias2; }
  }
  int t = threadIdx.x;
  int wid = t >> 6, lane = t & 63;
  int wm = (wid >> 1) * 64, wn = (wid & 1) * 64;
  int lr = lane & 15, lq = lane >> 4;
  int srow = lane >> 2, schunk = (lane & 3) * 8;

  f32x4 acc[4][4];
  #pragma unroll
  for (int i = 0; i < 4; ++i)
    #pragma unroll
    for (int j = 0; j < 4; ++j)
      acc[i][j] = (f32x4){0.f, 0.f, 0.f, 0.f};

  const u16* gA = A + (long long)(m0 + wid * 32 + srow) * K + schunk;
  const u16* gB = Bt + (long long)(n0 + wid * 32 + srow) * K + schunk;
  u16* lA = &sA[(wid * 32) * GBK];
  u16* lB = &sB[(wid * 32) * GBK];
  const long long rowskip = (long long)16 * K;

  for (int k0 = 0; k0 < K; k0 += GBK) {
    __builtin_amdgcn_global_load_lds(GCAST(gA + k0),           LCAST(lA),            16, 0, 0);
    __builtin_amdgcn_global_load_lds(GCAST(gA + k0 + rowskip), LCAST(lA + 16 * GBK), 16, 0, 0);
    __builtin_amdgcn_global_load_lds(GCAST(gB + k0),           LCAST(lB),            16, 0, 0);
    __builtin_amdgcn_global_load_lds(GCAST(gB + k0 + rowskip), LCAST(lB + 16 * GBK), 16, 0, 0);
    __syncthreads();
    short8 af[4], bf[4];
    #pragma unroll
    for (int i = 0; i < 4; ++i)
      af[i] = *(const short8*)&sA[(wm + i * 16 + lr) * GBK + lq * 8];
    #pragma unroll
    for (int j = 0; j < 4; ++j)
      bf[j] = *(const short8*)&sB[(wn + j * 16 + lr) * GBK + lq * 8];
    #pragma unroll
    for (int i = 0; i < 4; ++i)
      #pragma unroll
      for (int j = 0; j < 4; ++j)
        acc[i][j] = __builtin_amdgcn_mfma_f32_16x16x32_bf16(af[i], bf[j], acc[i][j], 0, 0, 0);
    __syncthreads();
  }

  #pragma unroll
  for (int i = 0; i < 4; ++i) {
    #pragma unroll
    for (int j = 0; j < 4; ++j) {
      int col = n0 + wn + j * 16 + lr;
      #pragma unroll
      for (int r = 0; r < 4; ++r) {
        int row = m0 + wm + i * 16 + lq * 4 + r;
        float v = acc[i][j][r];
        if (EPI == 0) {
          outB[(long long)row * N + col] = f2b(v + bias[col]);
        } else if (EPI == 1) {
          outF[(long long)row * N + col] = v;
        } else {
          outB[(long long)row * N + col] = f2b(v);
        }
      }
    }
  }
}

// ========== ring-4 counted-vmcnt 256x256 GEMM + reg prefetch + SGB =========
// R7-verbatim (benched 136-137.5us, MfmaUtil 45.5%, 0 conflicts). Converged:
// 8-phase ports (R8/R10/R15), 32x32 shape (R9), no-LDS (R12), smaller tiles
// (R13) and occupancy plays (R11) all measured slower on this problem.
#define SGB __builtin_amdgcn_sched_group_barrier
// masks: MFMA=0x008, VMEM_READ=0x020, DS_READ=0x100

__global__ __launch_bounds__(512, 2) void gemm_ring(
    const u16* __restrict__ A, const u16* __restrict__ Bt,
    float* __restrict__ outF, int M, int N, int K) {
  __shared__ u16 lds[4][2][8192];   // [ring][A/B][row*32 + slot*8] = 128 KiB

  // XCD-chunked swizzle: XCD owns contiguous N-chunk, M fastest inside.
  int nwg = gridDim.x * gridDim.y;
  int wg = blockIdx.y * gridDim.x + blockIdx.x;
  int cpx = nwg >> 3;
  int swz = (wg & 7) * cpx + (wg >> 3);
  int bx = swz & 7, by = swz >> 3;          // gridDim.x == 8
  int m0 = bx * 256, n0 = by * 256;

  int t = threadIdx.x;
  int w = t >> 6, lane = t & 63;
  int wr = w >> 2, wc = w & 3;              // wave tile: 128 rows x 64 cols
  int lr = lane & 15, lq = lane >> 4;
  int csw = (((lr >> 1) & 3) ^ lq) * 8;     // swizzled slot offset (u16)

  // staging source (pre-swizzled): thread t covers row (t>>2), slot (t&3)
  int srow = t >> 2;                                  // 0..127
  int sgc = (((srow >> 1) & 3) ^ (t & 3)) * 8;        // inverse-swizzled chunk
  const u16* pA0 = A + (long long)(m0 + srow) * K + sgc;
  const u16* pA1 = pA0 + (long long)128 * K;
  const u16* pB0 = Bt + (long long)(n0 + srow) * K + sgc;
  const u16* pB1 = pB0 + (long long)128 * K;
  const int lbase = (w * 16) * 32;           // wave-uniform LDS base (u16)

  f32x4 acc[8][4];
  #pragma unroll
  for (int i = 0; i < 8; ++i)
    #pragma unroll
    for (int j = 0; j < 4; ++j)
      acc[i][j] = (f32x4){0.f, 0.f, 0.f, 0.f};

  const int NT = K >> 5;   // K/32 tiles (=64)

  #define STAGE_TILE(KT, SB)                                                          \
    do {                                                                              \
      long long cofs = (long long)(KT) * 32;                                          \
      __builtin_amdgcn_global_load_lds(GCAST(pA0 + cofs), LCAST(&lds[SB][0][lbase]),            16, 0, 0); \
      __builtin_amdgcn_global_load_lds(GCAST(pA1 + cofs), LCAST(&lds[SB][0][lbase + 128 * 32]), 16, 0, 0); \
      __builtin_amdgcn_global_load_lds(GCAST(pB0 + cofs), LCAST(&lds[SB][1][lbase]),            16, 0, 0); \
      __builtin_amdgcn_global_load_lds(GCAST(pB1 + cofs), LCAST(&lds[SB][1][lbase + 128 * 32]), 16, 0, 0); \
    } while (0)

  #define RD_FRAGS(AF, BF, BUF) {                                                     \
    _Pragma("unroll")                                                                 \
    for (int i = 0; i < 8; ++i)                                                       \
      AF[i] = *(const short8*)&lds[BUF][0][(wr * 128 + i * 16 + lr) * 32 + csw];      \
    _Pragma("unroll")                                                                 \
    for (int j = 0; j < 4; ++j)                                                       \
      BF[j] = *(const short8*)&lds[BUF][1][(wc * 64 + j * 16 + lr) * 32 + csw]; }

  #define MFMA_NP(AF, BF) {                                                           \
    _Pragma("unroll")                                                                 \
    for (int i = 0; i < 8; ++i)                                                       \
      _Pragma("unroll")                                                               \
      for (int j = 0; j < 4; ++j)                                                     \
        acc[i][j] = __builtin_amdgcn_mfma_f32_16x16x32_bf16(AF[i], BF[j], acc[i][j], 0, 0, 0); }

  #define MFMA_BLK(AF, BF) {                                                          \
    __builtin_amdgcn_s_setprio(1);                                                    \
    MFMA_NP(AF, BF);                                                                  \
    __builtin_amdgcn_s_setprio(0); }

  // issue-interleave directive tail: {MFMA2} {DS2,MFMA4}x3 {VMEM4} {DS2,MFMA4}x3 {MFMA6}
  #define SGB_TAIL() {                                                                \
    SGB(0x008, 2, 0);                                                                 \
    SGB(0x100, 2, 0); SGB(0x008, 4, 0);                                               \
    SGB(0x100, 2, 0); SGB(0x008, 4, 0);                                               \
    SGB(0x100, 2, 0); SGB(0x008, 4, 0);                                               \
    SGB(0x020, 4, 0);                                                                 \
    SGB(0x100, 2, 0); SGB(0x008, 4, 0);                                               \
    SGB(0x100, 2, 0); SGB(0x008, 4, 0);                                               \
    SGB(0x100, 2, 0); SGB(0x008, 4, 0);                                               \
    SGB(0x008, 6, 0); }

  short8 afA[8], bfA[4], afB[8], bfB[4];

  // prologue: stage tiles 0,1,2 (12 loads); vmcnt(4) -> tiles 0,1 resident
  STAGE_TILE(0, 0);
  STAGE_TILE(1, 1);
  STAGE_TILE(2, 2);
  asm volatile("s_waitcnt vmcnt(4)" ::: "memory");
  __builtin_amdgcn_s_barrier();
  __builtin_amdgcn_sched_barrier(0);
  RD_FRAGS(afA, bfA, 0);                     // regs <- tile 0

  // steady state: 2 iters per body; invariant at iter kt entry:
  //   tiles <= kt+1 LDS-resident, tile kt+2's 4 loads outstanding.
  for (int kt = 0; kt + 4 < NT; kt += 2) {
    // ---- iter kt (cur = A)
    RD_FRAGS(afB, bfB, ((kt + 1) & 3));      // regs <- tile kt+1 (resident)
    STAGE_TILE(kt + 3, ((kt + 3) & 3));      // outstanding: kt+2, kt+3 (8)
    MFMA_NP(afA, bfA);                       // tile kt; interleaved via SGB
    SGB_TAIL();
    asm volatile("s_waitcnt vmcnt(4)" ::: "memory");   // tile kt+2 resident
    __builtin_amdgcn_s_barrier();
    __builtin_amdgcn_sched_barrier(0);
    // ---- iter kt+1 (cur = B)
    RD_FRAGS(afA, bfA, ((kt + 2) & 3));
    STAGE_TILE(kt + 4, ((kt + 4) & 3));
    MFMA_NP(afB, bfB);
    SGB_TAIL();
    asm volatile("s_waitcnt vmcnt(4)" ::: "memory");
    __builtin_amdgcn_s_barrier();
    __builtin_amdgcn_sched_barrier(0);
  }

  // tail: iters NT-4 .. NT-1 (steady loop ended at iter NT-5, parity even)
  // iter NT-4 (cur = A)
  RD_FRAGS(afB, bfB, ((NT - 3) & 3));
  STAGE_TILE(NT - 1, ((NT - 1) & 3));
  __builtin_amdgcn_sched_barrier(0);
  MFMA_BLK(afA, bfA);
  __builtin_amdgcn_sched_barrier(0);
  asm volatile("s_waitcnt vmcnt(4)" ::: "memory");     // tile NT-2 resident
  __builtin_amdgcn_s_barrier();
  __builtin_amdgcn_sched_barrier(0);
  // iter NT-3 (cur = B)
  RD_FRAGS(afA, bfA, ((NT - 2) & 3));
  __builtin_amdgcn_sched_barrier(0);
  MFMA_BLK(afB, bfB);
  __builtin_amdgcn_sched_barrier(0);
  asm volatile("s_waitcnt vmcnt(0)" ::: "memory");     // tile NT-1 resident
  __builtin_amdgcn_s_barrier();
  __builtin_amdgcn_sched_barrier(0);
  // iter NT-2 (cur = A)
  RD_FRAGS(afB, bfB, ((NT - 1) & 3));
  __builtin_amdgcn_sched_barrier(0);
  MFMA_BLK(afA, bfA);
  // iter NT-1 (cur = B) -- pure register MFMA, no barrier needed
  MFMA_BLK(afB, bfB);

  #undef STAGE_TILE
  #undef RD_FRAGS
  #undef MFMA_NP
  #undef MFMA_BLK
  #undef SGB_TAIL

  // epilogue: scatter cols -> per-batch layout
  #pragma unroll
  for (int i = 0; i < 8; ++i) {
    #pragma unroll
    for (int j = 0; j < 4; ++j) {
      int col = n0 + wc * 64 + j * 16 + lr;
      int b = col >> 9, kc = col & 511;
      float* ob = outF + (long long)b * ((long long)M * 512) + kc;
      #pragma unroll
      for (int r = 0; r < 4; ++r) {
        int row = m0 + wr * 128 + i * 16 + lq * 4 + r;
        ob[(long long)row * 512] = acc[i][j][r];
      }
    }
  }
}

// ---- transpose f32 [R][C] -> bf16 [C][R]  (fallback path only)
__global__ __launch_bounds__(256) void transpose_cvt(const float* __restrict__ src,
                                                     u16* __restrict__ dst, int R, int C) {
  __shared__ float tile[32][33];
  int c0 = blockIdx.x * 32, r0 = blockIdx.y * 32;
  int tx = threadIdx.x & 31, ty = threadIdx.x >> 5;
  #pragma unroll
  for (int i = 0; i < 32; i += 8)
    tile[ty + i][tx] = src[(long long)(r0 + ty + i) * C + c0 + tx];
  __syncthreads();
  #pragma unroll
  for (int i = 0; i < 32; i += 8)
    dst[(long long)(c0 + ty + i) * R + r0 + tx] = f2b(tile[tx][ty + i]);
}

// ============ fallback (round-1 kernel) for small-ws path ============
#define BMT 128
#define BNT 128
#define BKT 32
#define LDSP 40

template<int MODE>
__global__ __launch_bounds__(256) void gemm_bt(
    const u16* __restrict__ A, const u16* __restrict__ Bt,
    const float* __restrict__ bias, const float* __restrict__ fixmat,
    float* __restrict__ outF, u16* __restrict__ outB,
    int M, int N, int K, long long out_batch_stride, int bt_batch_stride) {
  __shared__ u16 sA[BMT][LDSP];
  __shared__ u16 sB[BNT][LDSP];
  int b = blockIdx.z;
  const u16* Bt_b = Bt + (long long)b * bt_batch_stride;
  const float* fixrow = (MODE == 2) ? (fixmat + (long long)b * K) : nullptr;
  float* out_b = (MODE == 1 || MODE == 2) ? (outF + (long long)b * out_batch_stride) : nullptr;

  int m0 = blockIdx.y * BMT, n0 = blockIdx.x * BNT;
  int t = threadIdx.x;
  int wid = t >> 6, lane = t & 63;
  int wm = (wid >> 1) * 64, wn = (wid & 1) * 64;
  int lr = lane & 15, lq = lane >> 4;

  f32x4 acc[4][4];
  #pragma unroll
  for (int i = 0; i < 4; ++i)
    #pragma unroll
    for (int j = 0; j < 4; ++j)
      acc[i][j] = (f32x4){0.f, 0.f, 0.f, 0.f};

  int srow = t >> 1, scg = (t & 1) * 16;

  for (int k0 = 0; k0 < K; k0 += BKT) {
    {
      const u16* src = A + (long long)(m0 + srow) * K + k0 + scg;
      short8 v0 = *(const short8*)(src);
      short8 v1 = *(const short8*)(src + 8);
      *(short8*)&sA[srow][scg] = v0;
      *(short8*)&sA[srow][scg + 8] = v1;
    }
    {
      const u16* src = Bt_b + (long long)(n0 + srow) * K + k0 + scg;
      short8 v0 = *(const short8*)(src);
      short8 v1 = *(const short8*)(src + 8);
      if (MODE == 2) {
        u16* p0 = (u16*)&v0; u16* p1 = (u16*)&v1;
        #pragma unroll
        for (int j = 0; j < 8; ++j) {
          p0[j] = f2b(b2f(p0[j]) * fixrow[k0 + scg + j]);
          p1[j] = f2b(b2f(p1[j]) * fixrow[k0 + scg + 8 + j]);
        }
      }
      *(short8*)&sB[srow][scg] = v0;
      *(short8*)&sB[srow][scg + 8] = v1;
    }
    __syncthreads();
    short8 af[4], bf[4];
    #pragma unroll
    for (int i = 0; i < 4; ++i)
      af[i] = *(const short8*)&sA[wm + i * 16 + lr][lq * 8];
    #pragma unroll
    for (int j = 0; j < 4; ++j)
      bf[j] = *(const short8*)&sB[wn + j * 16 + lr][lq * 8];
    #pragma unroll
    for (int i = 0; i < 4; ++i)
      #pragma unroll
      for (int j = 0; j < 4; ++j)
        acc[i][j] = __builtin_amdgcn_mfma_f32_16x16x32_bf16(af[i], bf[j], acc[i][j], 0, 0, 0);
    __syncthreads();
  }

  #pragma unroll
  for (int i = 0; i < 4; ++i) {
    #pragma unroll
    for (int j = 0; j < 4; ++j) {
      int col = n0 + wn + j * 16 + lr;
      #pragma unroll
      for (int r = 0; r < 4; ++r) {
        int row = m0 + wm + i * 16 + lq * 4 + r;
        float v = acc[i][j][r];
        if (MODE == 0) {
          v += bias[col];
          outB[(long long)row * N + col] = f2b(v);
        } else if (MODE == 3) {
          outB[(long long)row * N + col] = f2b(v);
        } else {
          out_b[(long long)row * N + col] = v;
        }
      }
    }
  }
}

extern "C" void kernel_launch(void* const* d_in, const int* in_sizes, int n_in,
                              void* d_out, int out_size, void* d_ws, size_t ws_size,
                              hipStream_t stream) {
  const float* main_feat  = (const float*)d_in[0];
  const float* other_feat = (const float*)d_in[1];
  const float* fix_feat   = (const float*)d_in[2];
  const int*   mask       = (const int*)d_in[3];
  const float* Wq         = (const float*)d_in[4];
  const float* bq         = (const float*)d_in[5];
  const float* Wk         = (const float*)d_in[6];
  const float* bk         = (const float*)d_in[7];
  float* out = (float*)d_out;

  char* ws = (char*)d_ws;
  const size_t OFF_MAINB  = 0;          // 2 MiB (mainB, otherB contiguous)
  const size_t OFF_OTHERB = 2097152;    // 2 MiB
  const size_t OFF_WQB    = 4194304;    // 512 KiB
  const size_t OFF_WKB    = 4718592;    // 512 KiB
  const size_t OFF_QB     = 5242880;    // 2 MiB (QB, KB contiguous)
  const size_t OFF_KB     = 7340032;    // 2 MiB
  const size_t OFF_OTB    = 9437184;    // 2 MiB (fallback only)
  const size_t OFF_P      = 11534336;   // 8 MiB (P bf16 [2048][2048])
  const size_t OFF_S      = 19922944;   // 8 MiB used (S bf16 [2048][2048])
  const size_t OFF_SCALED = 36700160;   // 64 MiB (scaled bf16 [32][512][2048])
  const size_t NEED_SCALED = OFF_SCALED + (size_t)BATCH_ * 512 * 2048 * 2;

  u16* mainB  = (u16*)(ws + OFF_MAINB);
  u16* otherB = (u16*)(ws + OFF_OTHERB);
  u16* WqB    = (u16*)(ws + OFF_WQB);
  u16* WkB    = (u16*)(ws + OFF_WKB);
  u16* QB     = (u16*)(ws + OFF_QB);
  u16* KB     = (u16*)(ws + OFF_KB);
  u16* oTB    = (u16*)(ws + OFF_OTB);
  u16* P      = (u16*)(ws + OFF_P);
  u16* S      = (u16*)(ws + OFF_S);
  u16* scaled = (u16*)(ws + OFF_SCALED);
  bool use_scaled = (ws_size >= NEED_SCALED);

  // 1) bf16 conversions (two dual launches)
  cvt_bf16_dual<<<2048, 256, 0, stream>>>(main_feat, mainB, 2048 * 512,
                                          other_feat, otherB, 2048 * 512);
  cvt_bf16_dual<<<512, 256, 0, stream>>>(Wq, WqB, 512 * 512,
                                         Wk, WkB, 512 * 512);

  if (use_scaled) {
    // 2) fused transpose+scale: scaled[b][k][o] (16B stores)
    transpose_scale<<<dim3(16, 64), 256, 0, stream>>>(other_feat, fix_feat, scaled);
    // 3) fused Q|K projection: M=4096 (rows 0..2047 -> Wq/bq, 2048.. -> Wk/bk)
    gemm_lds<0><<<dim3(4, 32), 256, 0, stream>>>(mainB, WqB, bq, WkB, bk,
        nullptr, QB, 4096, 512, 512);
    // 4) S = Q @ K^T (bf16 out; softmax applies 1/sqrt(512))
    gemm_lds<3><<<dim3(16, 16), 256, 0, stream>>>(QB, KB, nullptr, nullptr, nullptr,
        nullptr, S, 2048, 2048, 512);
    // 5) masked softmax -> P bf16
    softmax_mask<<<2048, 256, 0, stream>>>(S, mask, P, 2048);
    // 6) ring-4 pipelined GEMM (R7): out[b][m][k] via col scatter
    gemm_ring<<<dim3(8, 64), 512, 0, stream>>>(P, scaled, out, 2048, 16384, 2048);
  } else {
    // fallback: no 64MB scaled buffer
    transpose_cvt<<<dim3(16, 64), 256, 0, stream>>>(other_feat, oTB, 2048, 512);
    gemm_bt<0><<<dim3(4, 16, 1), 256, 0, stream>>>(mainB, WqB, bq, nullptr,
        nullptr, QB, 2048, 512, 512, 0, 0);
    gemm_bt<0><<<dim3(4, 16, 1), 256, 0, stream>>>(otherB, WkB, bk, nullptr,
        nullptr, KB, 2048, 512, 512, 0, 0);
    gemm_bt<3><<<dim3(16, 16, 1), 256, 0, stream>>>(QB, KB, nullptr, nullptr,
        nullptr, S, 2048, 2048, 512, 0, 0);
    softmax_mask<<<2048, 256, 0, stream>>>(S, mask, P, 2048);
    gemm_bt<2><<<dim3(4, 16, BATCH_), 256, 0, stream>>>(P, oTB, nullptr, fix_feat,
        out, nullptr, 2048, 512, 2048, 1048576LL, 0);
  }
}

// Round 18
// 163.007 us; speedup vs baseline: 1.0875x; 1.0623x over previous
//
#include <hip/hip_runtime.h>
#include <hip/hip_bf16.h>

typedef unsigned short u16;
typedef __attribute__((ext_vector_type(8))) short short8;
typedef __attribute__((ext_vector_type(4))) float f32x4;

#define BATCH_ 32

static __device__ __forceinline__ float b2f(u16 u) {
  union { unsigned int i; float f; } v; v.i = ((unsigned int)u) << 16; return v.f;
}
static __device__ __forceinline__ u16 f2b(float x) {
  unsigned int i = __float_as_uint(x);
  unsigned int r = (i + 0x7fffu + ((i >> 16) & 1u)) >> 16;
  return (u16)r;
}

#define GCAST(p) ((const __attribute__((address_space(1))) void*)(p))
#define LCAST(p) ((__attribute__((address_space(3))) void*)(p))

// ---- quad-source f32 -> bf16 (one launch for all four input arrays)
__global__ __launch_bounds__(256) void cvt_bf16_quad(
    const float* __restrict__ s1, u16* __restrict__ d1, int n1,
    const float* __restrict__ s2, u16* __restrict__ d2, int n2,
    const float* __restrict__ s3, u16* __restrict__ d3, int n3,
    const float* __restrict__ s4, u16* __restrict__ d4, int n4) {
  int i = (blockIdx.x * 256 + threadIdx.x) * 4;
  const float* s; u16* d; int idx;
  if (i < n1) { s = s1; d = d1; idx = i; }
  else if ((idx = i - n1) < n2) { s = s2; d = d2; }
  else if ((idx -= n2) < n3) { s = s3; d = d3; }
  else { idx -= n3; if (idx >= n4) return; s = s4; d = d4; }
  float4 v = *(const float4*)(s + idx);
  ushort4 o;
  o.x = f2b(v.x); o.y = f2b(v.y); o.z = f2b(v.z); o.w = f2b(v.w);
  *(ushort4*)(d + idx) = o;
}

// ---- FAT kernel: blocks 0..127 = fused Q|K projection GEMM (128x128/BK32,
// M=4096,N=512,K=512); blocks 128..1151 = transpose+scale
// (scaled[b][k][o] = other[o][k]*fix[b][o], short8 16B stores).
// Independent work co-scheduled in one launch: tscale's ~11us of memory
// traffic fills the CUs the 128-block proj GEMM leaves idle.
__global__ __launch_bounds__(256) void proj_and_scale(
    const u16* __restrict__ mainB, const u16* __restrict__ WqB,
    const float* __restrict__ bq, const u16* __restrict__ WkB,
    const float* __restrict__ bk, u16* __restrict__ QB,
    const float* __restrict__ other, const float* __restrict__ fix,
    u16* __restrict__ scaled) {
  __shared__ u16 smem[16384];   // proj: sA|sB (16KB); tscale: reuses as f32

  if (blockIdx.x < 128) {
    // ================= projection GEMM =================
    const int M = 4096, N = 512, K = 512;
    int bx = blockIdx.x & 3, by = blockIdx.x >> 2;
    const u16* Bt = WqB; const float* bias = bq;
    if (by >= 16) { Bt = WkB; bias = bk; }
    int m0 = by * 128, n0 = bx * 128;
    u16* sA = smem;             // [128*32]
    u16* sB = smem + 4096;      // [128*32]
    int t = threadIdx.x;
    int wid = t >> 6, lane = t & 63;
    int wm = (wid >> 1) * 64, wn = (wid & 1) * 64;
    int lr = lane & 15, lq = lane >> 4;
    int srow = lane >> 2, schunk = (lane & 3) * 8;

    f32x4 acc[4][4];
    #pragma unroll
    for (int i = 0; i < 4; ++i)
      #pragma unroll
      for (int j = 0; j < 4; ++j)
        acc[i][j] = (f32x4){0.f, 0.f, 0.f, 0.f};

    const u16* gA = mainB + (long long)(m0 + wid * 32 + srow) * K + schunk;
    const u16* gB = Bt + (long long)(n0 + wid * 32 + srow) * K + schunk;
    u16* lA = &sA[(wid * 32) * 32];
    u16* lB = &sB[(wid * 32) * 32];
    const long long rowskip = (long long)16 * K;

    for (int k0 = 0; k0 < K; k0 += 32) {
      __builtin_amdgcn_global_load_lds(GCAST(gA + k0),           LCAST(lA),           16, 0, 0);
      __builtin_amdgcn_global_load_lds(GCAST(gA + k0 + rowskip), LCAST(lA + 16 * 32), 16, 0, 0);
      __builtin_amdgcn_global_load_lds(GCAST(gB + k0),           LCAST(lB),           16, 0, 0);
      __builtin_amdgcn_global_load_lds(GCAST(gB + k0 + rowskip), LCAST(lB + 16 * 32), 16, 0, 0);
      __syncthreads();
      short8 af[4], bf[4];
      #pragma unroll
      for (int i = 0; i < 4; ++i)
        af[i] = *(const short8*)&sA[(wm + i * 16 + lr) * 32 + lq * 8];
      #pragma unroll
      for (int j = 0; j < 4; ++j)
        bf[j] = *(const short8*)&sB[(wn + j * 16 + lr) * 32 + lq * 8];
      #pragma unroll
      for (int i = 0; i < 4; ++i)
        #pragma unroll
        for (int j = 0; j < 4; ++j)
          acc[i][j] = __builtin_amdgcn_mfma_f32_16x16x32_bf16(af[i], bf[j], acc[i][j], 0, 0, 0);
      __syncthreads();
    }

    #pragma unroll
    for (int i = 0; i < 4; ++i) {
      #pragma unroll
      for (int j = 0; j < 4; ++j) {
        int col = n0 + wn + j * 16 + lr;
        #pragma unroll
        for (int r = 0; r < 4; ++r) {
          int row = m0 + wm + i * 16 + lq * 4 + r;
          QB[(long long)row * N + col] = f2b(acc[i][j][r] + bias[col]);
        }
      }
    }
  } else {
    // ================= transpose + scale =================
    int id = blockIdx.x - 128;               // 0..1023
    int k0 = (id & 15) * 32, o0 = (id >> 4) * 32;
    float (*tile)[33] = (float (*)[33])smem;           // [32][33] f32
    float (*fixs)[33] = (float (*)[33])(smem + 8448);  // [32][33] f32 (byte ofs 16896 <= 32768? no)
    // NOTE: smem is 16384 u16 = 32 KiB total; tile needs 32*33*4 = 4224 B,
    // fixs another 4224 B -> place fixs at u16 offset 2112 (4224 B).
    fixs = (float (*)[33])(smem + 2112);
    int tx = threadIdx.x & 31, ty = threadIdx.x >> 5;  // ty 0..7
    #pragma unroll
    for (int i = 0; i < 32; i += 8)
      tile[ty + i][tx] = other[(long long)(o0 + ty + i) * 512 + k0 + tx];
    #pragma unroll
    for (int i = 0; i < 32; i += 8)
      fixs[ty + i][tx] = fix[(long long)(ty + i) * 2048 + o0 + tx];
    __syncthreads();
    int og = (threadIdx.x & 3) * 8;                               // 0,8,16,24
    int k  = ((threadIdx.x >> 2) & 15) + ((threadIdx.x >> 7) << 4);
    int bh = (threadIdx.x >> 6) & 1;
    #pragma unroll
    for (int bb = 0; bb < 16; ++bb) {
      int b = bh * 16 + bb;
      short8 w;
      #pragma unroll
      for (int i = 0; i < 8; ++i)
        w[i] = (short)f2b(tile[og + i][k] * fixs[b][og + i]);
      *(short8*)(scaled + ((long long)(b * 512 + k0 + k) * 2048 + o0 + og)) = w;
    }
  }
}

// ---- masked row softmax on bf16 S, vectorized I/O (8 contiguous elems/thr)
__global__ __launch_bounds__(256) void softmax_mask(const u16* __restrict__ S,
                                                    const int* __restrict__ mask,
                                                    u16* __restrict__ P, int N) {
  const float scale = 0.044194173824159216f; // 1/sqrt(512)
  int row = blockIdx.x;
  int t = threadIdx.x;
  long long base = (long long)row * N + t * 8;
  short8 sv = *(const short8*)(S + base);
  int4 m0 = *(const int4*)(mask + base);
  int4 m1 = *(const int4*)(mask + base + 4);
  int msk[8] = {m0.x, m0.y, m0.z, m0.w, m1.x, m1.y, m1.z, m1.w};
  float vals[8];
  float mx = -3.0e38f;
  #pragma unroll
  for (int i = 0; i < 8; ++i) {
    vals[i] = b2f((u16)sv[i]) * scale;
    if (!msk[i]) mx = fmaxf(mx, vals[i]);
  }
  #pragma unroll
  for (int off = 32; off; off >>= 1) mx = fmaxf(mx, __shfl_xor(mx, off));
  __shared__ float sred[4];
  if ((t & 63) == 0) sred[t >> 6] = mx;
  __syncthreads();
  mx = fmaxf(fmaxf(sred[0], sred[1]), fmaxf(sred[2], sred[3]));
  __syncthreads();
  float e[8]; float sum = 0.f;
  #pragma unroll
  for (int i = 0; i < 8; ++i) {
    e[i] = msk[i] ? 0.f : __expf(vals[i] - mx);
    sum += e[i];
  }
  #pragma unroll
  for (int off = 32; off; off >>= 1) sum += __shfl_xor(sum, off);
  if ((t & 63) == 0) sred[t >> 6] = sum;
  __syncthreads();
  sum = sred[0] + sred[1] + sred[2] + sred[3];
  float inv = (sum > 0.f) ? (1.f / sum) : 0.f;
  short8 ov;
  #pragma unroll
  for (int i = 0; i < 8; ++i) ov[i] = (short)f2b(e[i] * inv);
  *(short8*)(P + base) = ov;
}

// ========== r2-proven 128x128 / BK=32 GEMM (S GEMM + fallback path) ========
// EPI 0: outB = bf16(C + bias[col]); dual-weight via second half of grid.y
// EPI 1: outF = C (f32)
// EPI 3: outB = bf16(C)
#define GBM 128
#define GBN 128
#define GBK 32

template<int EPI>
__global__ __launch_bounds__(256) void gemm_lds(
    const u16* __restrict__ A, const u16* __restrict__ Bt,
    const float* __restrict__ bias,
    const u16* __restrict__ Bt2, const float* __restrict__ bias2,
    float* __restrict__ outF, u16* __restrict__ outB,
    int M, int N, int K) {
  __shared__ u16 sA[GBM * GBK];
  __shared__ u16 sB[GBN * GBK];
  int m0 = blockIdx.y * GBM, n0 = blockIdx.x * GBN;
  if (EPI == 0) {
    if (2 * blockIdx.y >= gridDim.y) { Bt = Bt2; bias = bias2; }
  }
  int t = threadIdx.x;
  int wid = t >> 6, lane = t & 63;
  int wm = (wid >> 1) * 64, wn = (wid & 1) * 64;
  int lr = lane & 15, lq = lane >> 4;
  int srow = lane >> 2, schunk = (lane & 3) * 8;

  f32x4 acc[4][4];
  #pragma unroll
  for (int i = 0; i < 4; ++i)
    #pragma unroll
    for (int j = 0; j < 4; ++j)
      acc[i][j] = (f32x4){0.f, 0.f, 0.f, 0.f};

  const u16* gA = A + (long long)(m0 + wid * 32 + srow) * K + schunk;
  const u16* gB = Bt + (long long)(n0 + wid * 32 + srow) * K + schunk;
  u16* lA = &sA[(wid * 32) * GBK];
  u16* lB = &sB[(wid * 32) * GBK];
  const long long rowskip = (long long)16 * K;

  for (int k0 = 0; k0 < K; k0 += GBK) {
    __builtin_amdgcn_global_load_lds(GCAST(gA + k0),           LCAST(lA),            16, 0, 0);
    __builtin_amdgcn_global_load_lds(GCAST(gA + k0 + rowskip), LCAST(lA + 16 * GBK), 16, 0, 0);
    __builtin_amdgcn_global_load_lds(GCAST(gB + k0),           LCAST(lB),            16, 0, 0);
    __builtin_amdgcn_global_load_lds(GCAST(gB + k0 + rowskip), LCAST(lB + 16 * GBK), 16, 0, 0);
    __syncthreads();
    short8 af[4], bf[4];
    #pragma unroll
    for (int i = 0; i < 4; ++i)
      af[i] = *(const short8*)&sA[(wm + i * 16 + lr) * GBK + lq * 8];
    #pragma unroll
    for (int j = 0; j < 4; ++j)
      bf[j] = *(const short8*)&sB[(wn + j * 16 + lr) * GBK + lq * 8];
    #pragma unroll
    for (int i = 0; i < 4; ++i)
      #pragma unroll
      for (int j = 0; j < 4; ++j)
        acc[i][j] = __builtin_amdgcn_mfma_f32_16x16x32_bf16(af[i], bf[j], acc[i][j], 0, 0, 0);
    __syncthreads();
  }

  #pragma unroll
  for (int i = 0; i < 4; ++i) {
    #pragma unroll
    for (int j = 0; j < 4; ++j) {
      int col = n0 + wn + j * 16 + lr;
      #pragma unroll
      for (int r = 0; r < 4; ++r) {
        int row = m0 + wm + i * 16 + lq * 4 + r;
        float v = acc[i][j][r];
        if (EPI == 0) {
          outB[(long long)row * N + col] = f2b(v + bias[col]);
        } else if (EPI == 1) {
          outF[(long long)row * N + col] = v;
        } else {
          outB[(long long)row * N + col] = f2b(v);
        }
      }
    }
  }
}

// ========== ring-4 counted-vmcnt 256x256 GEMM + reg prefetch + SGB =========
// R7-verbatim (benched 136-139us, MfmaUtil 44-45.5%, 0 conflicts). Converged:
// 8-phase ports (R8/R10/R15), 32x32 shape (R9), no-LDS (R12), smaller tiles
// (R13) and occupancy plays (R11) all measured slower on this problem.
#define SGB __builtin_amdgcn_sched_group_barrier
// masks: MFMA=0x008, VMEM_READ=0x020, DS_READ=0x100

__global__ __launch_bounds__(512, 2) void gemm_ring(
    const u16* __restrict__ A, const u16* __restrict__ Bt,
    float* __restrict__ outF, int M, int N, int K) {
  __shared__ u16 lds[4][2][8192];   // [ring][A/B][row*32 + slot*8] = 128 KiB

  // XCD-chunked swizzle: XCD owns contiguous N-chunk, M fastest inside.
  int nwg = gridDim.x * gridDim.y;
  int wg = blockIdx.y * gridDim.x + blockIdx.x;
  int cpx = nwg >> 3;
  int swz = (wg & 7) * cpx + (wg >> 3);
  int bx = swz & 7, by = swz >> 3;          // gridDim.x == 8
  int m0 = bx * 256, n0 = by * 256;

  int t = threadIdx.x;
  int w = t >> 6, lane = t & 63;
  int wr = w >> 2, wc = w & 3;              // wave tile: 128 rows x 64 cols
  int lr = lane & 15, lq = lane >> 4;
  int csw = (((lr >> 1) & 3) ^ lq) * 8;     // swizzled slot offset (u16)

  // staging source (pre-swizzled): thread t covers row (t>>2), slot (t&3)
  int srow = t >> 2;                                  // 0..127
  int sgc = (((srow >> 1) & 3) ^ (t & 3)) * 8;        // inverse-swizzled chunk
  const u16* pA0 = A + (long long)(m0 + srow) * K + sgc;
  const u16* pA1 = pA0 + (long long)128 * K;
  const u16* pB0 = Bt + (long long)(n0 + srow) * K + sgc;
  const u16* pB1 = pB0 + (long long)128 * K;
  const int lbase = (w * 16) * 32;           // wave-uniform LDS base (u16)

  f32x4 acc[8][4];
  #pragma unroll
  for (int i = 0; i < 8; ++i)
    #pragma unroll
    for (int j = 0; j < 4; ++j)
      acc[i][j] = (f32x4){0.f, 0.f, 0.f, 0.f};

  const int NT = K >> 5;   // K/32 tiles (=64)

  #define STAGE_TILE(KT, SB)                                                          \
    do {                                                                              \
      long long cofs = (long long)(KT) * 32;                                          \
      __builtin_amdgcn_global_load_lds(GCAST(pA0 + cofs), LCAST(&lds[SB][0][lbase]),            16, 0, 0); \
      __builtin_amdgcn_global_load_lds(GCAST(pA1 + cofs), LCAST(&lds[SB][0][lbase + 128 * 32]), 16, 0, 0); \
      __builtin_amdgcn_global_load_lds(GCAST(pB0 + cofs), LCAST(&lds[SB][1][lbase]),            16, 0, 0); \
      __builtin_amdgcn_global_load_lds(GCAST(pB1 + cofs), LCAST(&lds[SB][1][lbase + 128 * 32]), 16, 0, 0); \
    } while (0)

  #define RD_FRAGS(AF, BF, BUF) {                                                     \
    _Pragma("unroll")                                                                 \
    for (int i = 0; i < 8; ++i)                                                       \
      AF[i] = *(const short8*)&lds[BUF][0][(wr * 128 + i * 16 + lr) * 32 + csw];      \
    _Pragma("unroll")                                                                 \
    for (int j = 0; j < 4; ++j)                                                       \
      BF[j] = *(const short8*)&lds[BUF][1][(wc * 64 + j * 16 + lr) * 32 + csw]; }

  #define MFMA_NP(AF, BF) {                                                           \
    _Pragma("unroll")                                                                 \
    for (int i = 0; i < 8; ++i)                                                       \
      _Pragma("unroll")                                                               \
      for (int j = 0; j < 4; ++j)                                                     \
        acc[i][j] = __builtin_amdgcn_mfma_f32_16x16x32_bf16(AF[i], BF[j], acc[i][j], 0, 0, 0); }

  #define MFMA_BLK(AF, BF) {                                                          \
    __builtin_amdgcn_s_setprio(1);                                                    \
    MFMA_NP(AF, BF);                                                                  \
    __builtin_amdgcn_s_setprio(0); }

  // issue-interleave directive tail: {MFMA2} {DS2,MFMA4}x3 {VMEM4} {DS2,MFMA4}x3 {MFMA6}
  #define SGB_TAIL() {                                                                \
    SGB(0x008, 2, 0);                                                                 \
    SGB(0x100, 2, 0); SGB(0x008, 4, 0);                                               \
    SGB(0x100, 2, 0); SGB(0x008, 4, 0);                                               \
    SGB(0x100, 2, 0); SGB(0x008, 4, 0);                                               \
    SGB(0x020, 4, 0);                                                                 \
    SGB(0x100, 2, 0); SGB(0x008, 4, 0);                                               \
    SGB(0x100, 2, 0); SGB(0x008, 4, 0);                                               \
    SGB(0x100, 2, 0); SGB(0x008, 4, 0);                                               \
    SGB(0x008, 6, 0); }

  short8 afA[8], bfA[4], afB[8], bfB[4];

  // prologue: stage tiles 0,1,2 (12 loads); vmcnt(4) -> tiles 0,1 resident
  STAGE_TILE(0, 0);
  STAGE_TILE(1, 1);
  STAGE_TILE(2, 2);
  asm volatile("s_waitcnt vmcnt(4)" ::: "memory");
  __builtin_amdgcn_s_barrier();
  __builtin_amdgcn_sched_barrier(0);
  RD_FRAGS(afA, bfA, 0);                     // regs <- tile 0

  // steady state: 2 iters per body; invariant at iter kt entry:
  //   tiles <= kt+1 LDS-resident, tile kt+2's 4 loads outstanding.
  for (int kt = 0; kt + 4 < NT; kt += 2) {
    // ---- iter kt (cur = A)
    RD_FRAGS(afB, bfB, ((kt + 1) & 3));      // regs <- tile kt+1 (resident)
    STAGE_TILE(kt + 3, ((kt + 3) & 3));      // outstanding: kt+2, kt+3 (8)
    MFMA_NP(afA, bfA);                       // tile kt; interleaved via SGB
    SGB_TAIL();
    asm volatile("s_waitcnt vmcnt(4)" ::: "memory");   // tile kt+2 resident
    __builtin_amdgcn_s_barrier();
    __builtin_amdgcn_sched_barrier(0);
    // ---- iter kt+1 (cur = B)
    RD_FRAGS(afA, bfA, ((kt + 2) & 3));
    STAGE_TILE(kt + 4, ((kt + 4) & 3));
    MFMA_NP(afB, bfB);
    SGB_TAIL();
    asm volatile("s_waitcnt vmcnt(4)" ::: "memory");
    __builtin_amdgcn_s_barrier();
    __builtin_amdgcn_sched_barrier(0);
  }

  // tail: iters NT-4 .. NT-1 (steady loop ended at iter NT-5, parity even)
  // iter NT-4 (cur = A)
  RD_FRAGS(afB, bfB, ((NT - 3) & 3));
  STAGE_TILE(NT - 1, ((NT - 1) & 3));
  __builtin_amdgcn_sched_barrier(0);
  MFMA_BLK(afA, bfA);
  __builtin_amdgcn_sched_barrier(0);
  asm volatile("s_waitcnt vmcnt(4)" ::: "memory");     // tile NT-2 resident
  __builtin_amdgcn_s_barrier();
  __builtin_amdgcn_sched_barrier(0);
  // iter NT-3 (cur = B)
  RD_FRAGS(afA, bfA, ((NT - 2) & 3));
  __builtin_amdgcn_sched_barrier(0);
  MFMA_BLK(afB, bfB);
  __builtin_amdgcn_sched_barrier(0);
  asm volatile("s_waitcnt vmcnt(0)" ::: "memory");     // tile NT-1 resident
  __builtin_amdgcn_s_barrier();
  __builtin_amdgcn_sched_barrier(0);
  // iter NT-2 (cur = A)
  RD_FRAGS(afB, bfB, ((NT - 1) & 3));
  __builtin_amdgcn_sched_barrier(0);
  MFMA_BLK(afA, bfA);
  // iter NT-1 (cur = B) -- pure register MFMA, no barrier needed
  MFMA_BLK(afB, bfB);

  #undef STAGE_TILE
  #undef RD_FRAGS
  #undef MFMA_NP
  #undef MFMA_BLK
  #undef SGB_TAIL

  // epilogue: scatter cols -> per-batch layout
  #pragma unroll
  for (int i = 0; i < 8; ++i) {
    #pragma unroll
    for (int j = 0; j < 4; ++j) {
      int col = n0 + wc * 64 + j * 16 + lr;
      int b = col >> 9, kc = col & 511;
      float* ob = outF + (long long)b * ((long long)M * 512) + kc;
      #pragma unroll
      for (int r = 0; r < 4; ++r) {
        int row = m0 + wr * 128 + i * 16 + lq * 4 + r;
        ob[(long long)row * 512] = acc[i][j][r];
      }
    }
  }
}

// ---- transpose f32 [R][C] -> bf16 [C][R]  (fallback path only)
__global__ __launch_bounds__(256) void transpose_cvt(const float* __restrict__ src,
                                                     u16* __restrict__ dst, int R, int C) {
  __shared__ float tile[32][33];
  int c0 = blockIdx.x * 32, r0 = blockIdx.y * 32;
  int tx = threadIdx.x & 31, ty = threadIdx.x >> 5;
  #pragma unroll
  for (int i = 0; i < 32; i += 8)
    tile[ty + i][tx] = src[(long long)(r0 + ty + i) * C + c0 + tx];
  __syncthreads();
  #pragma unroll
  for (int i = 0; i < 32; i += 8)
    dst[(long long)(c0 + ty + i) * R + r0 + tx] = f2b(tile[tx][ty + i]);
}

// ============ fallback (round-1 kernel) for small-ws path ============
#define BMT 128
#define BNT 128
#define BKT 32
#define LDSP 40

template<int MODE>
__global__ __launch_bounds__(256) void gemm_bt(
    const u16* __restrict__ A, const u16* __restrict__ Bt,
    const float* __restrict__ bias, const float* __restrict__ fixmat,
    float* __restrict__ outF, u16* __restrict__ outB,
    int M, int N, int K, long long out_batch_stride, int bt_batch_stride) {
  __shared__ u16 sA[BMT][LDSP];
  __shared__ u16 sB[BNT][LDSP];
  int b = blockIdx.z;
  const u16* Bt_b = Bt + (long long)b * bt_batch_stride;
  const float* fixrow = (MODE == 2) ? (fixmat + (long long)b * K) : nullptr;
  float* out_b = (MODE == 1 || MODE == 2) ? (outF + (long long)b * out_batch_stride) : nullptr;

  int m0 = blockIdx.y * BMT, n0 = blockIdx.x * BNT;
  int t = threadIdx.x;
  int wid = t >> 6, lane = t & 63;
  int wm = (wid >> 1) * 64, wn = (wid & 1) * 64;
  int lr = lane & 15, lq = lane >> 4;

  f32x4 acc[4][4];
  #pragma unroll
  for (int i = 0; i < 4; ++i)
    #pragma unroll
    for (int j = 0; j < 4; ++j)
      acc[i][j] = (f32x4){0.f, 0.f, 0.f, 0.f};

  int srow = t >> 1, scg = (t & 1) * 16;

  for (int k0 = 0; k0 < K; k0 += BKT) {
    {
      const u16* src = A + (long long)(m0 + srow) * K + k0 + scg;
      short8 v0 = *(const short8*)(src);
      short8 v1 = *(const short8*)(src + 8);
      *(short8*)&sA[srow][scg] = v0;
      *(short8*)&sA[srow][scg + 8] = v1;
    }
    {
      const u16* src = Bt_b + (long long)(n0 + srow) * K + k0 + scg;
      short8 v0 = *(const short8*)(src);
      short8 v1 = *(const short8*)(src + 8);
      if (MODE == 2) {
        u16* p0 = (u16*)&v0; u16* p1 = (u16*)&v1;
        #pragma unroll
        for (int j = 0; j < 8; ++j) {
          p0[j] = f2b(b2f(p0[j]) * fixrow[k0 + scg + j]);
          p1[j] = f2b(b2f(p1[j]) * fixrow[k0 + scg + 8 + j]);
        }
      }
      *(short8*)&sB[srow][scg] = v0;
      *(short8*)&sB[srow][scg + 8] = v1;
    }
    __syncthreads();
    short8 af[4], bf[4];
    #pragma unroll
    for (int i = 0; i < 4; ++i)
      af[i] = *(const short8*)&sA[wm + i * 16 + lr][lq * 8];
    #pragma unroll
    for (int j = 0; j < 4; ++j)
      bf[j] = *(const short8*)&sB[wn + j * 16 + lr][lq * 8];
    #pragma unroll
    for (int i = 0; i < 4; ++i)
      #pragma unroll
      for (int j = 0; j < 4; ++j)
        acc[i][j] = __builtin_amdgcn_mfma_f32_16x16x32_bf16(af[i], bf[j], acc[i][j], 0, 0, 0);
    __syncthreads();
  }

  #pragma unroll
  for (int i = 0; i < 4; ++i) {
    #pragma unroll
    for (int j = 0; j < 4; ++j) {
      int col = n0 + wn + j * 16 + lr;
      #pragma unroll
      for (int r = 0; r < 4; ++r) {
        int row = m0 + wm + i * 16 + lq * 4 + r;
        float v = acc[i][j][r];
        if (MODE == 0) {
          v += bias[col];
          outB[(long long)row * N + col] = f2b(v);
        } else if (MODE == 3) {
          outB[(long long)row * N + col] = f2b(v);
        } else {
          out_b[(long long)row * N + col] = v;
        }
      }
    }
  }
}

extern "C" void kernel_launch(void* const* d_in, const int* in_sizes, int n_in,
                              void* d_out, int out_size, void* d_ws, size_t ws_size,
                              hipStream_t stream) {
  const float* main_feat  = (const float*)d_in[0];
  const float* other_feat = (const float*)d_in[1];
  const float* fix_feat   = (const float*)d_in[2];
  const int*   mask       = (const int*)d_in[3];
  const float* Wq         = (const float*)d_in[4];
  const float* bq         = (const float*)d_in[5];
  const float* Wk         = (const float*)d_in[6];
  const float* bk         = (const float*)d_in[7];
  float* out = (float*)d_out;

  char* ws = (char*)d_ws;
  const size_t OFF_MAINB  = 0;          // 2 MiB (mainB, otherB contiguous)
  const size_t OFF_OTHERB = 2097152;    // 2 MiB
  const size_t OFF_WQB    = 4194304;    // 512 KiB
  const size_t OFF_WKB    = 4718592;    // 512 KiB
  const size_t OFF_QB     = 5242880;    // 2 MiB (QB, KB contiguous)
  const size_t OFF_KB     = 7340032;    // 2 MiB
  const size_t OFF_OTB    = 9437184;    // 2 MiB (fallback only)
  const size_t OFF_P      = 11534336;   // 8 MiB (P bf16 [2048][2048])
  const size_t OFF_S      = 19922944;   // 8 MiB used (S bf16 [2048][2048])
  const size_t OFF_SCALED = 36700160;   // 64 MiB (scaled bf16 [32][512][2048])
  const size_t NEED_SCALED = OFF_SCALED + (size_t)BATCH_ * 512 * 2048 * 2;

  u16* mainB  = (u16*)(ws + OFF_MAINB);
  u16* otherB = (u16*)(ws + OFF_OTHERB);
  u16* WqB    = (u16*)(ws + OFF_WQB);
  u16* WkB    = (u16*)(ws + OFF_WKB);
  u16* QB     = (u16*)(ws + OFF_QB);
  u16* KB     = (u16*)(ws + OFF_KB);
  u16* oTB    = (u16*)(ws + OFF_OTB);
  u16* P      = (u16*)(ws + OFF_P);
  u16* S      = (u16*)(ws + OFF_S);
  u16* scaled = (u16*)(ws + OFF_SCALED);
  bool use_scaled = (ws_size >= NEED_SCALED);

  // 1) bf16 conversions: all four arrays in ONE launch
  cvt_bf16_quad<<<2688, 256, 0, stream>>>(
      main_feat, mainB, 2048 * 512, other_feat, otherB, 2048 * 512,
      Wq, WqB, 512 * 512, Wk, WkB, 512 * 512);

  if (use_scaled) {
    // 2) FAT launch: proj GEMM (blocks 0-127) + transpose_scale (128-1151)
    proj_and_scale<<<1152, 256, 0, stream>>>(mainB, WqB, bq, WkB, bk, QB,
                                             other_feat, fix_feat, scaled);
    // 3) S = Q @ K^T (bf16 out; softmax applies 1/sqrt(512))
    gemm_lds<3><<<dim3(16, 16), 256, 0, stream>>>(QB, KB, nullptr, nullptr, nullptr,
        nullptr, S, 2048, 2048, 512);
    // 4) masked softmax -> P bf16
    softmax_mask<<<2048, 256, 0, stream>>>(S, mask, P, 2048);
    // 5) ring-4 pipelined GEMM (R7): out[b][m][k] via col scatter
    gemm_ring<<<dim3(8, 64), 512, 0, stream>>>(P, scaled, out, 2048, 16384, 2048);
  } else {
    // fallback: no 64MB scaled buffer
    transpose_cvt<<<dim3(16, 64), 256, 0, stream>>>(other_feat, oTB, 2048, 512);
    gemm_bt<0><<<dim3(4, 16, 1), 256, 0, stream>>>(mainB, WqB, bq, nullptr,
        nullptr, QB, 2048, 512, 512, 0, 0);
    gemm_bt<0><<<dim3(4, 16, 1), 256, 0, stream>>>(otherB, WkB, bk, nullptr,
        nullptr, KB, 2048, 512, 512, 0, 0);
    gemm_bt<3><<<dim3(16, 16, 1), 256, 0, stream>>>(QB, KB, nullptr, nullptr,
        nullptr, S, 2048, 2048, 512, 0, 0);
    softmax_mask<<<2048, 256, 0, stream>>>(S, mask, P, 2048);
    gemm_bt<2><<<dim3(4, 16, BATCH_), 256, 0, stream>>>(P, oTB, nullptr, fix_feat,
        out, nullptr, 2048, 512, 2048, 1048576LL, 0);
  }
}